// Round 14
// baseline (2452.466 us; speedup 1.0000x reference)
//
#include <hip/hip_runtime.h>
#include <math.h>

#define L4 4096

typedef short bf16x8 __attribute__((ext_vector_type(8)));
typedef float f32x4 __attribute__((ext_vector_type(4)));

__device__ __forceinline__ unsigned short f2bf(float f) {
  unsigned u = __builtin_bit_cast(unsigned, f);
  return (unsigned short)((u + 0x7FFFu + ((u >> 16) & 1u)) >> 16);
}
__device__ __forceinline__ float bf2f(unsigned short h) {
  unsigned u = ((unsigned)h) << 16;
  return __builtin_bit_cast(float, u);
}
__device__ __forceinline__ unsigned pk2(float lo, float hi) {
  unsigned d;
  asm("v_cvt_pk_bf16_f32 %0, %1, %2" : "=v"(d) : "v"(lo), "v"(hi));
  return d;
}
__device__ __forceinline__ float fast_tanh(float x) {
  float e = __expf(2.f * x);
  return 1.f - 2.f * __builtin_amdgcn_rcpf(e + 1.f);
}

// ---------------- pack big conv weights: Apack[ks][frow][lane][8] + t-channel ----------------
__global__ __launch_bounds__(256) void pack_big(const float* __restrict__ cw,
                                                unsigned short* __restrict__ Apack,
                                                float* __restrict__ Tpack) {
  int gid = blockIdx.x * 256 + threadIdx.x;
  if (gid < 768) {
    int o = gid & 255, tap = gid >> 8;
    Tpack[tap * 256 + o] = cw[((size_t)o * 257) * 9 + 3 + tap];
  }
  if (gid >= 24 * 16 * 64) return;
  int ks = gid >> 10;
  int frow = (gid >> 6) & 15;
  int lane = gid & 63;
  int o = frow * 16 + (lane & 15);
  int tap = ks >> 3;
  int ib = ((ks & 7) << 5) + ((lane >> 4) << 3);
#pragma unroll
  for (int e = 0; e < 8; e++) {
    int i = ib + e;
    Apack[(size_t)gid * 8 + e] = f2bf(cw[((size_t)o * 257 + (i + 1)) * 9 + 3 + tap]);
  }
}

// ---------------- pack stem conv2 weights ----------------
__global__ __launch_bounds__(256) void pack_stem(const float* __restrict__ w2,
                                                 unsigned short* __restrict__ Apack) {
  int gid = blockIdx.x * 256 + threadIdx.x;
  if (gid >= 6 * 16 * 64) return;
  int ks = gid >> 10;
  int frow = (gid >> 6) & 15;
  int lane = gid & 63;
  int o = frow * 16 + (lane & 15);
  int tap = ks >> 1;
  int ib = ((ks & 1) << 5) + ((lane >> 4) << 3);
#pragma unroll
  for (int e = 0; e < 8; e++) {
    int i = ib + e;
    Apack[(size_t)gid * 8 + e] = f2bf(w2[((size_t)o * 64 + i) * 3 + tap]);
  }
}

// ---------------- stem conv1 ----------------
__global__ __launch_bounds__(256) void conv1_kernel(const float* __restrict__ x,
                                                    const float* __restrict__ w,
                                                    const float* __restrict__ bias,
                                                    unsigned short* __restrict__ out) {
  int idx = blockIdx.x * 256 + threadIdx.x;
  int l = idx & 4095;
  int c = (idx >> 12) & 63;
  int b = idx >> 18;
  const float* xb = x + (size_t)b * 4 * L4;
  const float* wc = w + c * 12;
  float acc = bias[c];
#pragma unroll
  for (int i = 0; i < 4; i++) {
    float x0 = (l > 0) ? xb[i * L4 + l - 1] : 0.f;
    float x1 = xb[i * L4 + l];
    float x2 = (l < 4095) ? xb[i * L4 + l + 1] : 0.f;
    acc += wc[i * 3] * x0 + wc[i * 3 + 1] * x1 + wc[i * 3 + 2] * x2;
  }
  out[idx] = f2bf(acc);
}

// ---------------- stats, bf16 input ----------------
__global__ __launch_bounds__(256) void stats_bf16_kernel(const unsigned short* __restrict__ in,
                                                         float* __restrict__ stats,
                                                         int unit_stride, int nrow,
                                                         int row_stride, int rowlen,
                                                         float inv_n) {
  int u = blockIdx.x;
  const unsigned short* base = in + (size_t)u * unit_stride;
  float s = 0.f, s2 = 0.f;
  for (int r = 0; r < nrow; r++) {
    const unsigned short* rowp = base + (size_t)r * row_stride;
    for (int j = threadIdx.x * 4; j < rowlen; j += 256 * 4) {
      ushort4 v = *(const ushort4*)(rowp + j);
      float va = bf2f(v.x), vb = bf2f(v.y), vc = bf2f(v.z), vd = bf2f(v.w);
      s += va + vb + vc + vd;
      s2 += va * va + vb * vb + vc * vc + vd * vd;
    }
  }
  __shared__ float sh[512];
  sh[threadIdx.x] = s;
  sh[256 + threadIdx.x] = s2;
  __syncthreads();
  for (int off = 128; off > 0; off >>= 1) {
    if (threadIdx.x < off) {
      sh[threadIdx.x] += sh[threadIdx.x + off];
      sh[256 + threadIdx.x] += sh[256 + threadIdx.x + off];
    }
    __syncthreads();
  }
  if (threadIdx.x == 0) {
    float m = sh[0] * inv_n;
    float var = sh[256] * inv_n - m * m;
    stats[u * 2] = m;
    stats[u * 2 + 1] = rsqrtf(var + 1e-5f);
  }
}

// ---------------- stem: BN1-affine + relu + bf16 + transpose to padded XT64 ----------------
__global__ __launch_bounds__(256) void act_transpose64(const unsigned short* __restrict__ inv,
                                                       const float* __restrict__ stats,
                                                       const float* __restrict__ gamma,
                                                       const float* __restrict__ beta,
                                                       unsigned short* __restrict__ Xt) {
  constexpr int C = 64;
  __shared__ unsigned short tile[64 * C];
  int bidx = blockIdx.x;
  int b = bidx >> 6;
  int lt = bidx & 63;
  int l0 = lt << 6;
  int t = threadIdx.x;
  int lanel = t & 63;
  int cq = t >> 6;
  for (int cp = 0; cp < C / 4; cp++) {
    int c = cp * 4 + cq;
    float m = stats[2 * c], rs = stats[2 * c + 1];
    float ga = gamma[c] * rs, be = beta[c] - m * ga;
    size_t gidx = ((size_t)b * C + c) * 4096 + l0 + lanel;
    float v = bf2f(inv[gidx]);
    float a = v * ga + be;
    float r = fmaxf(a, 0.f);
    int sw = (lanel & 15) << 2;
    tile[lanel * C + (c ^ sw)] = f2bf(r);
  }
  __syncthreads();
  constexpr int CH = C / 4;
  constexpr int RPP = 256 / CH;
  for (int p = 0; p < 64 / RPP; p++) {
    int r = p * RPP + t / CH;
    int ch = t % CH;
    int sw = (r & 15) << 2;
    ushort4 v = *(const ushort4*)&tile[r * C + ((ch * 4) ^ sw)];
    *(ushort4*)&Xt[((size_t)b * 4098 + 1 + l0 + r) * C + ch * 4] = v;
  }
  if (lt == 0) {
    if (t < C / 4) *(ushort4*)&Xt[((size_t)b * 4098 + 0) * C + t * 4] = make_ushort4(0, 0, 0, 0);
  } else if (lt == 63) {
    if (t < C / 4) *(ushort4*)&Xt[((size_t)b * 4098 + 4097) * C + t * 4] = make_ushort4(0, 0, 0, 0);
  }
}

// ---------------- fused MFMA conv-GEMM (early-issued staging loads) ----------------------
// Tile 256o x 64l, 512 thr (8 waves, wave = 32o x 64l). grid = 16b * 64 lt = 1024.
// Staging raw loads are issued BEFORE the phase-0 stats reduce (T14): HBM latency hides
// under the partial-reduce + ebias work; transform+ds_write happen after the barrier.
// OUT: 0 = T-layout bf16 + partials; 1 = C-layout fp32; 2 = C-layout bf16.
template <int NKS, int KLG, int CIN, int NORM, int ACT, int NCH, bool INBF, bool TCH, int OUT>
__global__ __launch_bounds__(512, 4) void gemm_T(const void* __restrict__ Bsrc,
                                                 const unsigned short* __restrict__ Apack,
                                                 const float* __restrict__ Pin,
                                                 const float* __restrict__ gng,
                                                 const float* __restrict__ gnb,
                                                 const float* __restrict__ Tpack,
                                                 const float* __restrict__ bias,
                                                 float tval,
                                                 void* __restrict__ outv,
                                                 float* __restrict__ Pout) {
  constexpr int CPR = CIN / 8;
  constexpr int CPRLG = (CIN == 256) ? 5 : 3;
  constexpr int ROWS = 66;
  constexpr int RPI = 512 >> CPRLG;
  constexpr int TOT = ROWS * CPR;
  constexpr int NIT = (TOT + 511) / 512;
  __shared__ unsigned short bsm[ROWS * CIN];
  __shared__ float gsm[32][2];
  __shared__ float ebias[256];
  __shared__ float psh[32][2];

  int tid = threadIdx.x;
  int lane = tid & 63;
  int wv = tid >> 6;
  int b = blockIdx.x >> 6;
  int lt = blockIdx.x & 63;
  int l_base = lt << 6;
  int wo0 = wv << 5;
  int col = lane & 15;
  int grp = lane >> 4;

  // ---- issue raw B-tile loads FIRST (latency hides under phase-0 work) ----
  int pl = tid & (CPR - 1);
  int row0s = tid >> CPRLG;
  int gch = pl ^ (row0s & 7);
  uint4 hA[NIT];
  uint4 hB[NIT];
#pragma unroll
  for (int it = 0; it < NIT; it++) {
    hA[it] = make_uint4(0, 0, 0, 0);
    if (NORM && !INBF) hB[it] = make_uint4(0, 0, 0, 0);
    int chunk = it * 512 + tid;
    if (chunk < TOT) {
      int row = row0s + it * RPI;
      if (NORM) {
        int gl = l_base - 1 + row;
        if (gl >= 0 && gl < 4096) {
          size_t base = ((size_t)b * 4096 + gl) * CIN + gch * 8;
          if (INBF) {
            hA[it] = *(const uint4*)((const unsigned short*)Bsrc + base);
          } else {
            hA[it] = *(const uint4*)((const float*)Bsrc + base);
            hB[it] = *(const uint4*)((const float*)Bsrc + base + 4);
          }
        }
      } else {
        hA[it] = *(const uint4*)((const unsigned short*)Bsrc +
                                 ((size_t)b * 4098 + l_base + row) * CIN + gch * 8);
      }
    }
  }

  // ---- phase 0: parallel GN-stat reduce + ebias precompute ----
  if (NORM) {
    int g = tid >> 4, j0 = tid & 15;
    const float* Pg = Pin + ((size_t)b * 32 + g) * 128;
    float s = 0.f, s2 = 0.f;
    for (int j = j0; j < NCH; j += 16) { s += Pg[j * 2]; s2 += Pg[j * 2 + 1]; }
#pragma unroll
    for (int off = 8; off; off >>= 1) { s += __shfl_down(s, off, 16); s2 += __shfl_down(s2, off, 16); }
    if (j0 == 0) {
      float m = s * (1.f / 32768.f);
      float var = s2 * (1.f / 32768.f) - m * m;
      gsm[g][0] = m;
      gsm[g][1] = rsqrtf(var + 1e-5f);
    }
  }
  if (tid < 256) {
    float e = bias[tid];
    if (TCH) e += tval * (Tpack[tid] + Tpack[256 + tid] + Tpack[512 + tid]);
    ebias[tid] = e;
  }
  if (OUT == 0 && tid >= 256 && tid < 288) { psh[tid - 256][0] = 0.f; psh[tid - 256][1] = 0.f; }
  __syncthreads();

  // ---- transform held registers + ds_write (linear LDS, source pre-swizzled) ----
  {
    float ga0 = 1.f, ga1 = 1.f, ga2 = 1.f, ga3 = 1.f, ga4 = 1.f, ga5 = 1.f, ga6 = 1.f, ga7 = 1.f;
    float be0 = 0.f, be1 = 0.f, be2 = 0.f, be3 = 0.f, be4 = 0.f, be5 = 0.f, be6 = 0.f, be7 = 0.f;
    if (NORM) {
      float m = gsm[gch][0], rs = gsm[gch][1];
      float4 g0 = *(const float4*)&gng[gch * 8];
      float4 g1 = *(const float4*)&gng[gch * 8 + 4];
      float4 b0 = *(const float4*)&gnb[gch * 8];
      float4 b1 = *(const float4*)&gnb[gch * 8 + 4];
      ga0 = g0.x * rs; ga1 = g0.y * rs; ga2 = g0.z * rs; ga3 = g0.w * rs;
      ga4 = g1.x * rs; ga5 = g1.y * rs; ga6 = g1.z * rs; ga7 = g1.w * rs;
      be0 = b0.x - m * ga0; be1 = b0.y - m * ga1; be2 = b0.z - m * ga2; be3 = b0.w - m * ga3;
      be4 = b1.x - m * ga4; be5 = b1.y - m * ga5; be6 = b1.z - m * ga6; be7 = b1.w - m * ga7;
    }
#define ACTF(a) ((ACT == 0) ? fmaxf((a), 0.f) : ((a) > 0.f ? (a) : __expf(a) - 1.f))
#pragma unroll
    for (int it = 0; it < NIT; it++) {
      int chunk = it * 512 + tid;
      if (chunk < TOT) {
        int row = row0s + it * RPI;
        uint4 w4;
        if (NORM) {
          int gl = l_base - 1 + row;
          if (gl >= 0 && gl < 4096) {
            float v0, v1, v2, v3, v4, v5, v6, v7;
            if (INBF) {
              v0 = bf2f((unsigned short)(hA[it].x & 0xFFFF)); v1 = bf2f((unsigned short)(hA[it].x >> 16));
              v2 = bf2f((unsigned short)(hA[it].y & 0xFFFF)); v3 = bf2f((unsigned short)(hA[it].y >> 16));
              v4 = bf2f((unsigned short)(hA[it].z & 0xFFFF)); v5 = bf2f((unsigned short)(hA[it].z >> 16));
              v6 = bf2f((unsigned short)(hA[it].w & 0xFFFF)); v7 = bf2f((unsigned short)(hA[it].w >> 16));
            } else {
              v0 = __builtin_bit_cast(float, hA[it].x);
              v1 = __builtin_bit_cast(float, hA[it].y);
              v2 = __builtin_bit_cast(float, hA[it].z);
              v3 = __builtin_bit_cast(float, hA[it].w);
              v4 = __builtin_bit_cast(float, hB[it].x);
              v5 = __builtin_bit_cast(float, hB[it].y);
              v6 = __builtin_bit_cast(float, hB[it].z);
              v7 = __builtin_bit_cast(float, hB[it].w);
            }
            float r0 = ACTF(v0 * ga0 + be0), r1 = ACTF(v1 * ga1 + be1);
            float r2 = ACTF(v2 * ga2 + be2), r3 = ACTF(v3 * ga3 + be3);
            float r4 = ACTF(v4 * ga4 + be4), r5 = ACTF(v5 * ga5 + be5);
            float r6 = ACTF(v6 * ga6 + be6), r7 = ACTF(v7 * ga7 + be7);
            w4.x = pk2(r0, r1); w4.y = pk2(r2, r3);
            w4.z = pk2(r4, r5); w4.w = pk2(r6, r7);
          } else {
            w4 = make_uint4(0, 0, 0, 0);
          }
        } else {
          w4 = hA[it];
        }
        *(uint4*)&bsm[(size_t)chunk * 8] = w4;
      }
    }
#undef ACTF
  }
  __syncthreads();

  // ---- MFMA loop ----
  const unsigned short* apk = Apack + (size_t)(wv * 2) * 512 + (size_t)lane * 8;

  f32x4 acc[2][4];
#pragma unroll
  for (int i = 0; i < 2; i++)
#pragma unroll
    for (int j = 0; j < 4; j++) acc[i][j] = (f32x4){0.f, 0.f, 0.f, 0.f};

  __builtin_amdgcn_s_setprio(1);
#pragma unroll
  for (int ks = 0; ks < NKS; ks++) {
    int tap = ks >> KLG;
    int cbase = (ks & ((1 << KLG) - 1)) << 2;
    int lr0 = col + tap;
    int cb = (cbase + grp) ^ (lr0 & 7);
    const unsigned short* bp = &bsm[((size_t)(lr0 << CPRLG) + cb) * 8];
    const unsigned short* ap = apk + (size_t)ks * 16 * 512;
    bf16x8 bfr[4], afr[2];
#pragma unroll
    for (int fc = 0; fc < 4; fc++) bfr[fc] = *(const bf16x8*)(bp + fc * 16 * CIN);
#pragma unroll
    for (int fo = 0; fo < 2; fo++) afr[fo] = *(const bf16x8*)(ap + fo * 512);
#pragma unroll
    for (int fo = 0; fo < 2; fo++)
#pragma unroll
      for (int fc = 0; fc < 4; fc++)
        acc[fo][fc] = __builtin_amdgcn_mfma_f32_16x16x32_bf16(afr[fo], bfr[fc], acc[fo][fc], 0, 0, 0);
  }
  __builtin_amdgcn_s_setprio(0);

  // ---- epilogue ----
  float ps = 0.f, ps2 = 0.f;
#pragma unroll
  for (int fo = 0; fo < 2; fo++) {
    int o0 = wo0 + fo * 16 + grp * 4;
    float eb0 = ebias[o0], eb1 = ebias[o0 + 1], eb2 = ebias[o0 + 2], eb3 = ebias[o0 + 3];
    float w0c0 = 0.f, w0c1 = 0.f, w0c2 = 0.f, w0c3 = 0.f;
    float w2c0 = 0.f, w2c1 = 0.f, w2c2 = 0.f, w2c3 = 0.f;
    if (TCH && lt == 0) {
      w0c0 = tval * Tpack[o0]; w0c1 = tval * Tpack[o0 + 1];
      w0c2 = tval * Tpack[o0 + 2]; w0c3 = tval * Tpack[o0 + 3];
    }
    if (TCH && lt == 63) {
      w2c0 = tval * Tpack[512 + o0]; w2c1 = tval * Tpack[512 + o0 + 1];
      w2c2 = tval * Tpack[512 + o0 + 2]; w2c3 = tval * Tpack[512 + o0 + 3];
    }
#pragma unroll
    for (int fc = 0; fc < 4; fc++) {
      int l = l_base + fc * 16 + col;
      float v0 = acc[fo][fc][0] + eb0;
      float v1 = acc[fo][fc][1] + eb1;
      float v2 = acc[fo][fc][2] + eb2;
      float v3 = acc[fo][fc][3] + eb3;
      if (TCH) {
        if (lt == 0 && l == 0) { v0 -= w0c0; v1 -= w0c1; v2 -= w0c2; v3 -= w0c3; }
        if (lt == 63 && l == 4095) { v0 -= w2c0; v1 -= w2c1; v2 -= w2c2; v3 -= w2c3; }
      }
      if (OUT == 0) {
        ps += v0 + v1 + v2 + v3;
        ps2 += v0 * v0 + v1 * v1 + v2 * v2 + v3 * v3;
        uint2 pk = make_uint2(pk2(v0, v1), pk2(v2, v3));
        *(uint2*)((unsigned short*)outv + ((size_t)b * 4096 + l) * 256 + o0) = pk;
      } else if (OUT == 1) {
        float* op = (float*)outv + ((size_t)b * 256 + o0) * 4096 + l;
        op[0] = v0; op[4096] = v1; op[8192] = v2; op[12288] = v3;
      } else {
        unsigned short* op = (unsigned short*)outv + ((size_t)b * 256 + o0) * 4096 + l;
        op[0] = f2bf(v0); op[4096] = f2bf(v1); op[8192] = f2bf(v2); op[12288] = f2bf(v3);
      }
    }
    if (OUT == 0) {
      float s = ps, s2 = ps2;
#pragma unroll
      for (int off = 8; off; off >>= 1) {
        s += __shfl_down(s, off, 16);
        s2 += __shfl_down(s2, off, 16);
      }
      if (col == 0) {
        int g = wv * 4 + fo * 2 + (grp >> 1);
        atomicAdd(&psh[g][0], s);
        atomicAdd(&psh[g][1], s2);
      }
      ps = 0.f; ps2 = 0.f;
    }
  }

  if (OUT == 0) {
    __syncthreads();
    if (tid < 32) {
      size_t pi = ((size_t)b * 32 + tid) * 128 + (size_t)lt * 2;
      Pout[pi] = psh[tid][0];
      Pout[pi + 1] = psh[tid][1];
    }
  }
}

// ---------------- stem: BN2-affine + fast-tanh (bf16 in), C->T transpose, y0 bf16 --------
__global__ __launch_bounds__(512) void bn_tanh_T(const unsigned short* __restrict__ Q,
                                                 const float* __restrict__ stats,
                                                 const float* __restrict__ gamma,
                                                 const float* __restrict__ beta,
                                                 unsigned short* __restrict__ Y,
                                                 float* __restrict__ P1) {
  int tid = threadIdx.x;
  int b = blockIdx.x >> 5;
  int seg = blockIdx.x & 31;
  int c = tid >> 1;
  float m = stats[2 * c], rs = stats[2 * c + 1];
  float ga = gamma[c] * rs, be = beta[c] - m * ga;
  __shared__ float psh[32][2];
  if (tid < 32) { psh[tid][0] = 0.f; psh[tid][1] = 0.f; }
  __syncthreads();
  float s = 0.f, s2 = 0.f;
  for (int it = 0; it < 16; it++) {
    int l4 = (tid & 1) + it * 2;
    int l0 = seg * 128 + l4 * 4;
    ushort4 v = *(const ushort4*)&Q[((size_t)b * 256 + c) * 4096 + l0];
    float r0 = fast_tanh(bf2f(v.x) * ga + be);
    float r1 = fast_tanh(bf2f(v.y) * ga + be);
    float r2 = fast_tanh(bf2f(v.z) * ga + be);
    float r3 = fast_tanh(bf2f(v.w) * ga + be);
    Y[((size_t)b * 4096 + l0 + 0) * 256 + c] = f2bf(r0);
    Y[((size_t)b * 4096 + l0 + 1) * 256 + c] = f2bf(r1);
    Y[((size_t)b * 4096 + l0 + 2) * 256 + c] = f2bf(r2);
    Y[((size_t)b * 4096 + l0 + 3) * 256 + c] = f2bf(r3);
    s += r0 + r1 + r2 + r3;
    s2 += r0 * r0 + r1 * r1 + r2 * r2 + r3 * r3;
  }
#pragma unroll
  for (int off = 8; off; off >>= 1) { s += __shfl_down(s, off, 16); s2 += __shfl_down(s2, off, 16); }
  if ((tid & 15) == 0) {
    int g = c >> 3;
    atomicAdd(&psh[g][0], s);
    atomicAdd(&psh[g][1], s2);
  }
  __syncthreads();
  if (tid < 32) {
    size_t pi = ((size_t)b * 32 + tid) * 128 + (size_t)seg * 2;
    P1[pi] = psh[tid][0];
    P1[pi + 1] = psh[tid][1];
  }
}

// ---------------- combine (T layout, bf16 state): GN3-affine(F) + Heun + P1 partials ----
template <int MODE>
__global__ __launch_bounds__(512) void combine_T(const unsigned short* __restrict__ F,
                                                 const float* __restrict__ P3,
                                                 const float* __restrict__ gng,
                                                 const float* __restrict__ gnb,
                                                 const unsigned short* __restrict__ Yin,
                                                 unsigned short* __restrict__ Out1,
                                                 unsigned short* __restrict__ OutB,
                                                 float* __restrict__ P1) {
  __shared__ float gsm[32][2];
  __shared__ float gabe[256][2];
  __shared__ float psh[32][2];
  int tid = threadIdx.x;
  int b = blockIdx.x >> 5;
  int seg = blockIdx.x & 31;
  {
    int g = tid >> 4, j0 = tid & 15;
    const float* Pg = P3 + ((size_t)b * 32 + g) * 128;
    float s = 0.f, s2 = 0.f;
    for (int j = j0; j < 64; j += 16) { s += Pg[j * 2]; s2 += Pg[j * 2 + 1]; }
#pragma unroll
    for (int off = 8; off; off >>= 1) { s += __shfl_down(s, off, 16); s2 += __shfl_down(s2, off, 16); }
    if (j0 == 0) {
      float m = s * (1.f / 32768.f);
      float var = s2 * (1.f / 32768.f) - m * m;
      gsm[g][0] = m;
      gsm[g][1] = rsqrtf(var + 1e-5f);
    }
  }
  __syncthreads();
  if (tid < 256) {
    float m = gsm[tid >> 3][0], rs = gsm[tid >> 3][1];
    float ga = gng[tid] * rs;
    gabe[tid][0] = ga;
    gabe[tid][1] = gnb[tid] - m * ga;
  }
  if (tid >= 256 && tid < 288) { psh[tid - 256][0] = 0.f; psh[tid - 256][1] = 0.f; }
  __syncthreads();

  size_t base4 = ((size_t)b * 4096 + seg * 128) * 64;
  int c0 = (tid << 2) & 255;
  int g = c0 >> 3;
  float ga0 = gabe[c0][0], be0 = gabe[c0][1];
  float ga1 = gabe[c0 + 1][0], be1 = gabe[c0 + 1][1];
  float ga2 = gabe[c0 + 2][0], be2 = gabe[c0 + 2][1];
  float ga3 = gabe[c0 + 3][0], be3 = gabe[c0 + 3][1];
  float s = 0.f, s2 = 0.f;
  for (int i = tid; i < 8192; i += 512) {
    size_t idx4 = base4 + i;
    ushort4 fv = ((const ushort4*)F)[idx4];
    ushort4 yv = ((const ushort4*)Yin)[idx4];
    float y0 = bf2f(yv.x), y1v = bf2f(yv.y), y2 = bf2f(yv.z), y3 = bf2f(yv.w);
    float f0 = bf2f(fv.x) * ga0 + be0;
    float f1 = bf2f(fv.y) * ga1 + be1;
    float f2 = bf2f(fv.z) * ga2 + be2;
    float f3 = bf2f(fv.w) * ga3 + be3;
    float yn0 = y0 + (MODE == 0 ? 0.125f : 0.0625f) * f0;
    float yn1 = y1v + (MODE == 0 ? 0.125f : 0.0625f) * f1;
    float yn2 = y2 + (MODE == 0 ? 0.125f : 0.0625f) * f2;
    float yn3 = y3 + (MODE == 0 ? 0.125f : 0.0625f) * f3;
    ((uint2*)Out1)[idx4] = make_uint2(pk2(yn0, yn1), pk2(yn2, yn3));
    if (MODE == 0) {
      float yb0 = y0 + 0.0625f * f0;
      float yb1 = y1v + 0.0625f * f1;
      float yb2 = y2 + 0.0625f * f2;
      float yb3 = y3 + 0.0625f * f3;
      ((uint2*)OutB)[idx4] = make_uint2(pk2(yb0, yb1), pk2(yb2, yb3));
    }
    s += yn0 + yn1 + yn2 + yn3;
    s2 += yn0 * yn0 + yn1 * yn1 + yn2 * yn2 + yn3 * yn3;
  }
  s += __shfl_xor(s, 1);
  s2 += __shfl_xor(s2, 1);
  if ((tid & 1) == 0) {
    atomicAdd(&psh[g][0], s);
    atomicAdd(&psh[g][1], s2);
  }
  __syncthreads();
  if (tid < 32) {
    size_t pi = ((size_t)b * 32 + tid) * 128 + (size_t)seg * 2;
    P1[pi] = psh[tid][0];
    P1[pi + 1] = psh[tid][1];
  }
}

// ---------------- final: T-layout bf16 -> C-layout fp32 (d_out) ----------------
__global__ __launch_bounds__(256) void transpose_final(const unsigned short* __restrict__ Y,
                                                       float* __restrict__ out) {
  __shared__ unsigned short tile[64 * 260];
  int b = blockIdx.x >> 6;
  int lt = blockIdx.x & 63;
  int t = threadIdx.x;
  for (int i = t; i < 4096; i += 256) {
    int r = i >> 6;
    int c4 = (i & 63) << 2;
    ushort4 v = *(const ushort4*)&Y[((size_t)b * 4096 + lt * 64 + r) * 256 + c4];
    *(ushort4*)&tile[r * 260 + c4] = v;
  }
  __syncthreads();
  for (int i = t; i < 4096; i += 256) {
    int c = i >> 4;
    int l4 = (i & 15) << 2;
    float4 v;
    v.x = bf2f(tile[(l4 + 0) * 260 + c]);
    v.y = bf2f(tile[(l4 + 1) * 260 + c]);
    v.z = bf2f(tile[(l4 + 2) * 260 + c]);
    v.w = bf2f(tile[(l4 + 3) * 260 + c]);
    *(float4*)&out[((size_t)b * 256 + c) * 4096 + lt * 64 + l4] = v;
  }
}

extern "C" void kernel_launch(void* const* d_in, const int* in_sizes, int n_in,
                              void* d_out, int out_size, void* d_ws, size_t ws_size,
                              hipStream_t stream) {
  const float* x = (const float*)d_in[0];
  const float* w1 = (const float*)d_in[1];
  const float* b1 = (const float*)d_in[2];
  const float* bn1_g = (const float*)d_in[3];
  const float* bn1_b = (const float*)d_in[4];
  const float* w2 = (const float*)d_in[5];
  const float* b2 = (const float*)d_in[6];
  const float* bn2_g = (const float*)d_in[7];
  const float* bn2_b = (const float*)d_in[8];
  const float* cw1 = (const float*)d_in[9];
  const float* cb1 = (const float*)d_in[10];
  const float* gn1_g = (const float*)d_in[11];
  const float* gn1_b = (const float*)d_in[12];
  const float* gn2_g = (const float*)d_in[13];
  const float* gn2_b = (const float*)d_in[14];
  const float* cw2 = (const float*)d_in[15];
  const float* cb2 = (const float*)d_in[16];
  const float* gn3_g = (const float*)d_in[17];
  const float* gn3_b = (const float*)d_in[18];

  const size_t SZ = (size_t)16 * 256 * 4096;

  char* p = (char*)d_ws;
  unsigned short* Ybf = (unsigned short*)p;  p += SZ * 2;   // bf16 T state
  unsigned short* C1 = (unsigned short*)p;   p += SZ * 2;
  unsigned short* Fb = (unsigned short*)p;   p += SZ * 2;
  unsigned short* APK1 = (unsigned short*)p; p += (size_t)24 * 16 * 64 * 8 * 2;
  unsigned short* APK2 = (unsigned short*)p; p += (size_t)24 * 16 * 64 * 8 * 2;
  unsigned short* APKS = (unsigned short*)p; p += (size_t)6 * 16 * 64 * 8 * 2;
  float* TP1 = (float*)p;                    p += 768 * 4;
  float* TP2 = (float*)p;                    p += 768 * 4;
  float* STATS = (float*)p;                  p += 1024 * 4;
  float* P1 = (float*)p;                     p += (size_t)16 * 32 * 128 * 4;
  float* P2 = (float*)p;                     p += (size_t)16 * 32 * 128 * 4;
  float* P3 = (float*)p;                     p += (size_t)16 * 32 * 128 * 4;

  unsigned short* Qbf = (unsigned short*)d_out;   // stem conv2-out scratch (bf16 C-layout)
  unsigned short* Y1 = (unsigned short*)d_out;    // y1 bf16 (first 32 MB)
  unsigned short* YB = Y1 + SZ;                   // ybase bf16 (second 32 MB)

  // ---- weight packing ----
  pack_big<<<96, 256, 0, stream>>>(cw1, APK1, TP1);
  pack_big<<<96, 256, 0, stream>>>(cw2, APK2, TP2);
  pack_stem<<<24, 256, 0, stream>>>(w2, APKS);

  // ---- stem ----
  conv1_kernel<<<16384, 256, 0, stream>>>(x, w1, b1, C1);
  stats_bf16_kernel<<<64, 256, 0, stream>>>(C1, STATS, 4096, 16, 64 * 4096, 4096, 1.f / 65536.f);
  act_transpose64<<<1024, 256, 0, stream>>>(C1, STATS, bn1_g, bn1_b, Fb);
  gemm_T<6, 1, 64, 0, 0, 32, true, false, 2><<<1024, 512, 0, stream>>>(
      Fb, APKS, nullptr, nullptr, nullptr, nullptr, b2, 0.f, Qbf, nullptr);
  stats_bf16_kernel<<<256, 256, 0, stream>>>(Qbf, STATS, 4096, 16, 256 * 4096, 4096, 1.f / 65536.f);
  bn_tanh_T<<<512, 512, 0, stream>>>(Qbf, STATS, bn2_g, bn2_b, Ybf, P1);

  // ---- ODE: 8 steps (pred + 2 corr), bf16 T state in Ybf ----
  const float H = 0.125f;
  for (int i = 0; i < 8; i++) {
    float t = i * H;
    gemm_T<24, 3, 256, 1, 0, 32, true, true, 0><<<1024, 512, 0, stream>>>(
        Ybf, APK1, P1, gn1_g, gn1_b, TP1, cb1, t, C1, P2);
    gemm_T<24, 3, 256, 1, 1, 64, true, true, 0><<<1024, 512, 0, stream>>>(
        C1, APK2, P2, gn2_g, gn2_b, TP2, cb2, t, Fb, P3);
    combine_T<0><<<512, 512, 0, stream>>>(Fb, P3, gn3_g, gn3_b, Ybf, Y1, YB, P1);
    for (int c = 0; c < 2; c++) {
      gemm_T<24, 3, 256, 1, 0, 32, true, true, 0><<<1024, 512, 0, stream>>>(
          Y1, APK1, P1, gn1_g, gn1_b, TP1, cb1, t + H, C1, P2);
      gemm_T<24, 3, 256, 1, 1, 64, true, true, 0><<<1024, 512, 0, stream>>>(
          C1, APK2, P2, gn2_g, gn2_b, TP2, cb2, t + H, Fb, P3);
      if (c == 0)
        combine_T<1><<<512, 512, 0, stream>>>(Fb, P3, gn3_g, gn3_b, YB, Y1, nullptr, P1);
      else
        combine_T<2><<<512, 512, 0, stream>>>(Fb, P3, gn3_g, gn3_b, YB, Ybf, nullptr, P1);
    }
  }

  // ---- final: transpose bf16 T state -> d_out C layout fp32 ----
  transpose_final<<<1024, 256, 0, stream>>>(Ybf, (float*)d_out);
}

// Round 15
// 2266.697 us; speedup vs baseline: 1.0820x; 1.0820x over previous
//
#include <hip/hip_runtime.h>
#include <math.h>

#define L4 4096

typedef short bf16x8 __attribute__((ext_vector_type(8)));
typedef float f32x4 __attribute__((ext_vector_type(4)));

__device__ __forceinline__ unsigned short f2bf(float f) {
  unsigned u = __builtin_bit_cast(unsigned, f);
  return (unsigned short)((u + 0x7FFFu + ((u >> 16) & 1u)) >> 16);
}
__device__ __forceinline__ float bf2f(unsigned short h) {
  unsigned u = ((unsigned)h) << 16;
  return __builtin_bit_cast(float, u);
}
__device__ __forceinline__ unsigned pk2(float lo, float hi) {
  unsigned d;
  asm("v_cvt_pk_bf16_f32 %0, %1, %2" : "=v"(d) : "v"(lo), "v"(hi));
  return d;
}
__device__ __forceinline__ float fast_tanh(float x) {
  float e = __expf(2.f * x);
  return 1.f - 2.f * __builtin_amdgcn_rcpf(e + 1.f);
}

// ---------------- pack big conv weights: Apack[ks][frow][lane][8] + t-channel ----------------
__global__ __launch_bounds__(256) void pack_big(const float* __restrict__ cw,
                                                unsigned short* __restrict__ Apack,
                                                float* __restrict__ Tpack) {
  int gid = blockIdx.x * 256 + threadIdx.x;
  if (gid < 768) {
    int o = gid & 255, tap = gid >> 8;
    Tpack[tap * 256 + o] = cw[((size_t)o * 257) * 9 + 3 + tap];
  }
  if (gid >= 24 * 16 * 64) return;
  int ks = gid >> 10;
  int frow = (gid >> 6) & 15;
  int lane = gid & 63;
  int o = frow * 16 + (lane & 15);
  int tap = ks >> 3;
  int ib = ((ks & 7) << 5) + ((lane >> 4) << 3);
#pragma unroll
  for (int e = 0; e < 8; e++) {
    int i = ib + e;
    Apack[(size_t)gid * 8 + e] = f2bf(cw[((size_t)o * 257 + (i + 1)) * 9 + 3 + tap]);
  }
}

// ---------------- pack stem conv2 weights ----------------
__global__ __launch_bounds__(256) void pack_stem(const float* __restrict__ w2,
                                                 unsigned short* __restrict__ Apack) {
  int gid = blockIdx.x * 256 + threadIdx.x;
  if (gid >= 6 * 16 * 64) return;
  int ks = gid >> 10;
  int frow = (gid >> 6) & 15;
  int lane = gid & 63;
  int o = frow * 16 + (lane & 15);
  int tap = ks >> 1;
  int ib = ((ks & 1) << 5) + ((lane >> 4) << 3);
#pragma unroll
  for (int e = 0; e < 8; e++) {
    int i = ib + e;
    Apack[(size_t)gid * 8 + e] = f2bf(w2[((size_t)o * 64 + i) * 3 + tap]);
  }
}

// ---------------- stem conv1 ----------------
__global__ __launch_bounds__(256) void conv1_kernel(const float* __restrict__ x,
                                                    const float* __restrict__ w,
                                                    const float* __restrict__ bias,
                                                    unsigned short* __restrict__ out) {
  int idx = blockIdx.x * 256 + threadIdx.x;
  int l = idx & 4095;
  int c = (idx >> 12) & 63;
  int b = idx >> 18;
  const float* xb = x + (size_t)b * 4 * L4;
  const float* wc = w + c * 12;
  float acc = bias[c];
#pragma unroll
  for (int i = 0; i < 4; i++) {
    float x0 = (l > 0) ? xb[i * L4 + l - 1] : 0.f;
    float x1 = xb[i * L4 + l];
    float x2 = (l < 4095) ? xb[i * L4 + l + 1] : 0.f;
    acc += wc[i * 3] * x0 + wc[i * 3 + 1] * x1 + wc[i * 3 + 2] * x2;
  }
  out[idx] = f2bf(acc);
}

// ---------------- stats, bf16 input ----------------
__global__ __launch_bounds__(256) void stats_bf16_kernel(const unsigned short* __restrict__ in,
                                                         float* __restrict__ stats,
                                                         int unit_stride, int nrow,
                                                         int row_stride, int rowlen,
                                                         float inv_n) {
  int u = blockIdx.x;
  const unsigned short* base = in + (size_t)u * unit_stride;
  float s = 0.f, s2 = 0.f;
  for (int r = 0; r < nrow; r++) {
    const unsigned short* rowp = base + (size_t)r * row_stride;
    for (int j = threadIdx.x * 4; j < rowlen; j += 256 * 4) {
      ushort4 v = *(const ushort4*)(rowp + j);
      float va = bf2f(v.x), vb = bf2f(v.y), vc = bf2f(v.z), vd = bf2f(v.w);
      s += va + vb + vc + vd;
      s2 += va * va + vb * vb + vc * vc + vd * vd;
    }
  }
  __shared__ float sh[512];
  sh[threadIdx.x] = s;
  sh[256 + threadIdx.x] = s2;
  __syncthreads();
  for (int off = 128; off > 0; off >>= 1) {
    if (threadIdx.x < off) {
      sh[threadIdx.x] += sh[threadIdx.x + off];
      sh[256 + threadIdx.x] += sh[256 + threadIdx.x + off];
    }
    __syncthreads();
  }
  if (threadIdx.x == 0) {
    float m = sh[0] * inv_n;
    float var = sh[256] * inv_n - m * m;
    stats[u * 2] = m;
    stats[u * 2 + 1] = rsqrtf(var + 1e-5f);
  }
}

// ---------------- stem: BN1-affine + relu + bf16 + transpose to padded XT64 ----------------
__global__ __launch_bounds__(256) void act_transpose64(const unsigned short* __restrict__ inv,
                                                       const float* __restrict__ stats,
                                                       const float* __restrict__ gamma,
                                                       const float* __restrict__ beta,
                                                       unsigned short* __restrict__ Xt) {
  constexpr int C = 64;
  __shared__ unsigned short tile[64 * C];
  int bidx = blockIdx.x;
  int b = bidx >> 6;
  int lt = bidx & 63;
  int l0 = lt << 6;
  int t = threadIdx.x;
  int lanel = t & 63;
  int cq = t >> 6;
  for (int cp = 0; cp < C / 4; cp++) {
    int c = cp * 4 + cq;
    float m = stats[2 * c], rs = stats[2 * c + 1];
    float ga = gamma[c] * rs, be = beta[c] - m * ga;
    size_t gidx = ((size_t)b * C + c) * 4096 + l0 + lanel;
    float v = bf2f(inv[gidx]);
    float a = v * ga + be;
    float r = fmaxf(a, 0.f);
    int sw = (lanel & 15) << 2;
    tile[lanel * C + (c ^ sw)] = f2bf(r);
  }
  __syncthreads();
  constexpr int CH = C / 4;
  constexpr int RPP = 256 / CH;
  for (int p = 0; p < 64 / RPP; p++) {
    int r = p * RPP + t / CH;
    int ch = t % CH;
    int sw = (r & 15) << 2;
    ushort4 v = *(const ushort4*)&tile[r * C + ((ch * 4) ^ sw)];
    *(ushort4*)&Xt[((size_t)b * 4098 + 1 + l0 + r) * C + ch * 4] = v;
  }
  if (lt == 0) {
    if (t < C / 4) *(ushort4*)&Xt[((size_t)b * 4098 + 0) * C + t * 4] = make_ushort4(0, 0, 0, 0);
  } else if (lt == 63) {
    if (t < C / 4) *(ushort4*)&Xt[((size_t)b * 4098 + 4097) * C + t * 4] = make_ushort4(0, 0, 0, 0);
  }
}

// ---------------- fused MFMA conv-GEMM: 4 waves of 64o x 64l (B-read amortized 2x) -------
// Tile 256o x 64l, 256 thr (4 waves). grid = 16b * 64 lt = 1024, 4 blocks/CU.
// Per ks per wave: 4 A-loads (L2), 4 ds_read_b128, 16 MFMAs (LDS pipe demand halved).
// OUT: 0 = T-layout bf16 + partials; 1 = C-layout fp32; 2 = C-layout bf16.
template <int NKS, int KLG, int CIN, int NORM, int ACT, int NCH, bool INBF, bool TCH, int OUT>
__global__ __launch_bounds__(256, 4) void gemm_T(const void* __restrict__ Bsrc,
                                                 const unsigned short* __restrict__ Apack,
                                                 const float* __restrict__ Pin,
                                                 const float* __restrict__ gng,
                                                 const float* __restrict__ gnb,
                                                 const float* __restrict__ Tpack,
                                                 const float* __restrict__ bias,
                                                 float tval,
                                                 void* __restrict__ outv,
                                                 float* __restrict__ Pout) {
  constexpr int CPR = CIN / 8;
  constexpr int CPRLG = (CIN == 256) ? 5 : 3;
  constexpr int ROWS = 66;
  constexpr int RPI = 256 >> CPRLG;   // rows per staging iteration (8 or 32; %8==0)
  constexpr int TOT = ROWS * CPR;
  constexpr int NIT = (TOT + 255) / 256;
  __shared__ unsigned short bsm[ROWS * CIN];
  __shared__ float gsm[32][2];
  __shared__ float ebias[256];
  __shared__ float psh[32][2];

  int tid = threadIdx.x;
  int lane = tid & 63;
  int wv = tid >> 6;           // 0..3
  int b = blockIdx.x >> 6;
  int lt = blockIdx.x & 63;
  int l_base = lt << 6;
  int wo0 = wv << 6;           // wave covers 64 o
  int col = lane & 15;
  int grp = lane >> 4;

  // ---- phase 0: parallel GN-stat reduce (8-lane groups) + ebias precompute ----
  if (NORM) {
    int g = tid >> 3, j0 = tid & 7;
    const float* Pg = Pin + ((size_t)b * 32 + g) * 128;
    float s = 0.f, s2 = 0.f;
    for (int j = j0; j < NCH; j += 8) { s += Pg[j * 2]; s2 += Pg[j * 2 + 1]; }
#pragma unroll
    for (int off = 4; off; off >>= 1) { s += __shfl_down(s, off, 8); s2 += __shfl_down(s2, off, 8); }
    if (j0 == 0) {
      float m = s * (1.f / 32768.f);
      float var = s2 * (1.f / 32768.f) - m * m;
      gsm[g][0] = m;
      gsm[g][1] = rsqrtf(var + 1e-5f);
    }
  }
  {
    float e = bias[tid];
    if (TCH) e += tval * (Tpack[tid] + Tpack[256 + tid] + Tpack[512 + tid]);
    ebias[tid] = e;
  }
  if (OUT == 0 && tid < 32) { psh[tid][0] = 0.f; psh[tid][1] = 0.f; }
  __syncthreads();

  // ---- phase 1: stage B tile; linear LDS writes, source pre-swizzled ----
  {
    int pl = tid & (CPR - 1);
    int row0 = tid >> CPRLG;
    int gch = pl ^ (row0 & 7);        // fixed global channel-chunk for this lane
    float ga0 = 1.f, ga1 = 1.f, ga2 = 1.f, ga3 = 1.f, ga4 = 1.f, ga5 = 1.f, ga6 = 1.f, ga7 = 1.f;
    float be0 = 0.f, be1 = 0.f, be2 = 0.f, be3 = 0.f, be4 = 0.f, be5 = 0.f, be6 = 0.f, be7 = 0.f;
    if (NORM) {
      float m = gsm[gch][0], rs = gsm[gch][1];
      float4 g0 = *(const float4*)&gng[gch * 8];
      float4 g1 = *(const float4*)&gng[gch * 8 + 4];
      float4 b0 = *(const float4*)&gnb[gch * 8];
      float4 b1 = *(const float4*)&gnb[gch * 8 + 4];
      ga0 = g0.x * rs; ga1 = g0.y * rs; ga2 = g0.z * rs; ga3 = g0.w * rs;
      ga4 = g1.x * rs; ga5 = g1.y * rs; ga6 = g1.z * rs; ga7 = g1.w * rs;
      be0 = b0.x - m * ga0; be1 = b0.y - m * ga1; be2 = b0.z - m * ga2; be3 = b0.w - m * ga3;
      be4 = b1.x - m * ga4; be5 = b1.y - m * ga5; be6 = b1.z - m * ga6; be7 = b1.w - m * ga7;
    }
#define ACTF(a) ((ACT == 0) ? fmaxf((a), 0.f) : ((a) > 0.f ? (a) : __expf(a) - 1.f))
#pragma unroll
    for (int it = 0; it < NIT; it++) {
      int chunk = it * 256 + tid;
      if (chunk < TOT) {
        int row = row0 + it * RPI;
        uint4 w4;
        if (NORM) {
          int gl = l_base - 1 + row;
          if (gl >= 0 && gl < 4096) {
            size_t base = ((size_t)b * 4096 + gl) * CIN + gch * 8;
            float v0, v1, v2, v3, v4, v5, v6, v7;
            if (INBF) {
              uint4 raw = *(const uint4*)((const unsigned short*)Bsrc + base);
              v0 = bf2f((unsigned short)(raw.x & 0xFFFF)); v1 = bf2f((unsigned short)(raw.x >> 16));
              v2 = bf2f((unsigned short)(raw.y & 0xFFFF)); v3 = bf2f((unsigned short)(raw.y >> 16));
              v4 = bf2f((unsigned short)(raw.z & 0xFFFF)); v5 = bf2f((unsigned short)(raw.z >> 16));
              v6 = bf2f((unsigned short)(raw.w & 0xFFFF)); v7 = bf2f((unsigned short)(raw.w >> 16));
            } else {
              float4 r0 = *(const float4*)((const float*)Bsrc + base);
              float4 r1 = *(const float4*)((const float*)Bsrc + base + 4);
              v0 = r0.x; v1 = r0.y; v2 = r0.z; v3 = r0.w;
              v4 = r1.x; v5 = r1.y; v6 = r1.z; v7 = r1.w;
            }
            float r0 = ACTF(v0 * ga0 + be0), r1 = ACTF(v1 * ga1 + be1);
            float r2 = ACTF(v2 * ga2 + be2), r3 = ACTF(v3 * ga3 + be3);
            float r4 = ACTF(v4 * ga4 + be4), r5 = ACTF(v5 * ga5 + be5);
            float r6 = ACTF(v6 * ga6 + be6), r7 = ACTF(v7 * ga7 + be7);
            w4.x = pk2(r0, r1); w4.y = pk2(r2, r3);
            w4.z = pk2(r4, r5); w4.w = pk2(r6, r7);
          } else {
            w4 = make_uint4(0, 0, 0, 0);
          }
        } else {
          w4 = *(const uint4*)((const unsigned short*)Bsrc +
                               ((size_t)b * 4098 + l_base + row) * CIN + gch * 8);
        }
        *(uint4*)&bsm[(size_t)chunk * 8] = w4;
      }
    }
#undef ACTF
  }
  __syncthreads();

  // ---- phase 2: MFMA loop (4 B ds_reads feed 16 MFMAs per ks) ----
  const unsigned short* apk = Apack + (size_t)(wv * 4) * 512 + (size_t)lane * 8;

  f32x4 acc[4][4];
#pragma unroll
  for (int i = 0; i < 4; i++)
#pragma unroll
    for (int j = 0; j < 4; j++) acc[i][j] = (f32x4){0.f, 0.f, 0.f, 0.f};

  __builtin_amdgcn_s_setprio(1);
#pragma unroll
  for (int ks = 0; ks < NKS; ks++) {
    int tap = ks >> KLG;
    int cbase = (ks & ((1 << KLG) - 1)) << 2;
    int lr0 = col + tap;
    int cb = (cbase + grp) ^ (lr0 & 7);
    const unsigned short* bp = &bsm[((size_t)(lr0 << CPRLG) + cb) * 8];
    const unsigned short* ap = apk + (size_t)ks * 16 * 512;
    bf16x8 bfr[4], afr[4];
#pragma unroll
    for (int fc = 0; fc < 4; fc++) bfr[fc] = *(const bf16x8*)(bp + fc * 16 * CIN);
#pragma unroll
    for (int fo = 0; fo < 4; fo++) afr[fo] = *(const bf16x8*)(ap + fo * 512);
#pragma unroll
    for (int fo = 0; fo < 4; fo++)
#pragma unroll
      for (int fc = 0; fc < 4; fc++)
        acc[fo][fc] = __builtin_amdgcn_mfma_f32_16x16x32_bf16(afr[fo], bfr[fc], acc[fo][fc], 0, 0, 0);
  }
  __builtin_amdgcn_s_setprio(0);

  // ---- epilogue ----
  float ps = 0.f, ps2 = 0.f;
#pragma unroll
  for (int fo = 0; fo < 4; fo++) {
    int o0 = wo0 + fo * 16 + grp * 4;
    float eb0 = ebias[o0], eb1 = ebias[o0 + 1], eb2 = ebias[o0 + 2], eb3 = ebias[o0 + 3];
    float w0c0 = 0.f, w0c1 = 0.f, w0c2 = 0.f, w0c3 = 0.f;
    float w2c0 = 0.f, w2c1 = 0.f, w2c2 = 0.f, w2c3 = 0.f;
    if (TCH && lt == 0) {
      w0c0 = tval * Tpack[o0]; w0c1 = tval * Tpack[o0 + 1];
      w0c2 = tval * Tpack[o0 + 2]; w0c3 = tval * Tpack[o0 + 3];
    }
    if (TCH && lt == 63) {
      w2c0 = tval * Tpack[512 + o0]; w2c1 = tval * Tpack[512 + o0 + 1];
      w2c2 = tval * Tpack[512 + o0 + 2]; w2c3 = tval * Tpack[512 + o0 + 3];
    }
#pragma unroll
    for (int fc = 0; fc < 4; fc++) {
      int l = l_base + fc * 16 + col;
      float v0 = acc[fo][fc][0] + eb0;
      float v1 = acc[fo][fc][1] + eb1;
      float v2 = acc[fo][fc][2] + eb2;
      float v3 = acc[fo][fc][3] + eb3;
      if (TCH) {
        if (lt == 0 && l == 0) { v0 -= w0c0; v1 -= w0c1; v2 -= w0c2; v3 -= w0c3; }
        if (lt == 63 && l == 4095) { v0 -= w2c0; v1 -= w2c1; v2 -= w2c2; v3 -= w2c3; }
      }
      if (OUT == 0) {
        ps += v0 + v1 + v2 + v3;
        ps2 += v0 * v0 + v1 * v1 + v2 * v2 + v3 * v3;
        uint2 pk = make_uint2(pk2(v0, v1), pk2(v2, v3));
        *(uint2*)((unsigned short*)outv + ((size_t)b * 4096 + l) * 256 + o0) = pk;
      } else if (OUT == 1) {
        float* op = (float*)outv + ((size_t)b * 256 + o0) * 4096 + l;
        op[0] = v0; op[4096] = v1; op[8192] = v2; op[12288] = v3;
      } else {
        unsigned short* op = (unsigned short*)outv + ((size_t)b * 256 + o0) * 4096 + l;
        op[0] = f2bf(v0); op[4096] = f2bf(v1); op[8192] = f2bf(v2); op[12288] = f2bf(v3);
      }
    }
    if (OUT == 0) {
      float s = ps, s2 = ps2;
#pragma unroll
      for (int off = 8; off; off >>= 1) {
        s += __shfl_down(s, off, 16);
        s2 += __shfl_down(s2, off, 16);
      }
      if (col == 0) {
        int g = wv * 8 + fo * 2 + (grp >> 1);
        atomicAdd(&psh[g][0], s);
        atomicAdd(&psh[g][1], s2);
      }
      ps = 0.f; ps2 = 0.f;
    }
  }

  if (OUT == 0) {
    __syncthreads();
    if (tid < 32) {
      size_t pi = ((size_t)b * 32 + tid) * 128 + (size_t)lt * 2;
      Pout[pi] = psh[tid][0];
      Pout[pi + 1] = psh[tid][1];
    }
  }
}

// ---------------- stem: BN2-affine + fast-tanh (bf16 in), C->T transpose, y0 bf16 --------
__global__ __launch_bounds__(512) void bn_tanh_T(const unsigned short* __restrict__ Q,
                                                 const float* __restrict__ stats,
                                                 const float* __restrict__ gamma,
                                                 const float* __restrict__ beta,
                                                 unsigned short* __restrict__ Y,
                                                 float* __restrict__ P1) {
  int tid = threadIdx.x;
  int b = blockIdx.x >> 5;
  int seg = blockIdx.x & 31;
  int c = tid >> 1;
  float m = stats[2 * c], rs = stats[2 * c + 1];
  float ga = gamma[c] * rs, be = beta[c] - m * ga;
  __shared__ float psh[32][2];
  if (tid < 32) { psh[tid][0] = 0.f; psh[tid][1] = 0.f; }
  __syncthreads();
  float s = 0.f, s2 = 0.f;
  for (int it = 0; it < 16; it++) {
    int l4 = (tid & 1) + it * 2;
    int l0 = seg * 128 + l4 * 4;
    ushort4 v = *(const ushort4*)&Q[((size_t)b * 256 + c) * 4096 + l0];
    float r0 = fast_tanh(bf2f(v.x) * ga + be);
    float r1 = fast_tanh(bf2f(v.y) * ga + be);
    float r2 = fast_tanh(bf2f(v.z) * ga + be);
    float r3 = fast_tanh(bf2f(v.w) * ga + be);
    Y[((size_t)b * 4096 + l0 + 0) * 256 + c] = f2bf(r0);
    Y[((size_t)b * 4096 + l0 + 1) * 256 + c] = f2bf(r1);
    Y[((size_t)b * 4096 + l0 + 2) * 256 + c] = f2bf(r2);
    Y[((size_t)b * 4096 + l0 + 3) * 256 + c] = f2bf(r3);
    s += r0 + r1 + r2 + r3;
    s2 += r0 * r0 + r1 * r1 + r2 * r2 + r3 * r3;
  }
#pragma unroll
  for (int off = 8; off; off >>= 1) { s += __shfl_down(s, off, 16); s2 += __shfl_down(s2, off, 16); }
  if ((tid & 15) == 0) {
    int g = c >> 3;
    atomicAdd(&psh[g][0], s);
    atomicAdd(&psh[g][1], s2);
  }
  __syncthreads();
  if (tid < 32) {
    size_t pi = ((size_t)b * 32 + tid) * 128 + (size_t)seg * 2;
    P1[pi] = psh[tid][0];
    P1[pi + 1] = psh[tid][1];
  }
}

// ---------------- combine (T layout, bf16 state): GN3-affine(F) + Heun + P1 partials ----
template <int MODE>
__global__ __launch_bounds__(512) void combine_T(const unsigned short* __restrict__ F,
                                                 const float* __restrict__ P3,
                                                 const float* __restrict__ gng,
                                                 const float* __restrict__ gnb,
                                                 const unsigned short* __restrict__ Yin,
                                                 unsigned short* __restrict__ Out1,
                                                 unsigned short* __restrict__ OutB,
                                                 float* __restrict__ P1) {
  __shared__ float gsm[32][2];
  __shared__ float gabe[256][2];
  __shared__ float psh[32][2];
  int tid = threadIdx.x;
  int b = blockIdx.x >> 5;
  int seg = blockIdx.x & 31;
  {
    int g = tid >> 4, j0 = tid & 15;
    const float* Pg = P3 + ((size_t)b * 32 + g) * 128;
    float s = 0.f, s2 = 0.f;
    for (int j = j0; j < 64; j += 16) { s += Pg[j * 2]; s2 += Pg[j * 2 + 1]; }
#pragma unroll
    for (int off = 8; off; off >>= 1) { s += __shfl_down(s, off, 16); s2 += __shfl_down(s2, off, 16); }
    if (j0 == 0) {
      float m = s * (1.f / 32768.f);
      float var = s2 * (1.f / 32768.f) - m * m;
      gsm[g][0] = m;
      gsm[g][1] = rsqrtf(var + 1e-5f);
    }
  }
  __syncthreads();
  if (tid < 256) {
    float m = gsm[tid >> 3][0], rs = gsm[tid >> 3][1];
    float ga = gng[tid] * rs;
    gabe[tid][0] = ga;
    gabe[tid][1] = gnb[tid] - m * ga;
  }
  if (tid >= 256 && tid < 288) { psh[tid - 256][0] = 0.f; psh[tid - 256][1] = 0.f; }
  __syncthreads();

  size_t base4 = ((size_t)b * 4096 + seg * 128) * 64;
  int c0 = (tid << 2) & 255;
  int g = c0 >> 3;
  float ga0 = gabe[c0][0], be0 = gabe[c0][1];
  float ga1 = gabe[c0 + 1][0], be1 = gabe[c0 + 1][1];
  float ga2 = gabe[c0 + 2][0], be2 = gabe[c0 + 2][1];
  float ga3 = gabe[c0 + 3][0], be3 = gabe[c0 + 3][1];
  float s = 0.f, s2 = 0.f;
  for (int i = tid; i < 8192; i += 512) {
    size_t idx4 = base4 + i;
    ushort4 fv = ((const ushort4*)F)[idx4];
    ushort4 yv = ((const ushort4*)Yin)[idx4];
    float y0 = bf2f(yv.x), y1v = bf2f(yv.y), y2 = bf2f(yv.z), y3 = bf2f(yv.w);
    float f0 = bf2f(fv.x) * ga0 + be0;
    float f1 = bf2f(fv.y) * ga1 + be1;
    float f2 = bf2f(fv.z) * ga2 + be2;
    float f3 = bf2f(fv.w) * ga3 + be3;
    float yn0 = y0 + (MODE == 0 ? 0.125f : 0.0625f) * f0;
    float yn1 = y1v + (MODE == 0 ? 0.125f : 0.0625f) * f1;
    float yn2 = y2 + (MODE == 0 ? 0.125f : 0.0625f) * f2;
    float yn3 = y3 + (MODE == 0 ? 0.125f : 0.0625f) * f3;
    ((uint2*)Out1)[idx4] = make_uint2(pk2(yn0, yn1), pk2(yn2, yn3));
    if (MODE == 0) {
      float yb0 = y0 + 0.0625f * f0;
      float yb1 = y1v + 0.0625f * f1;
      float yb2 = y2 + 0.0625f * f2;
      float yb3 = y3 + 0.0625f * f3;
      ((uint2*)OutB)[idx4] = make_uint2(pk2(yb0, yb1), pk2(yb2, yb3));
    }
    s += yn0 + yn1 + yn2 + yn3;
    s2 += yn0 * yn0 + yn1 * yn1 + yn2 * yn2 + yn3 * yn3;
  }
  s += __shfl_xor(s, 1);
  s2 += __shfl_xor(s2, 1);
  if ((tid & 1) == 0) {
    atomicAdd(&psh[g][0], s);
    atomicAdd(&psh[g][1], s2);
  }
  __syncthreads();
  if (tid < 32) {
    size_t pi = ((size_t)b * 32 + tid) * 128 + (size_t)seg * 2;
    P1[pi] = psh[tid][0];
    P1[pi + 1] = psh[tid][1];
  }
}

// ---------------- final: T-layout bf16 -> C-layout fp32 (d_out) ----------------
__global__ __launch_bounds__(256) void transpose_final(const unsigned short* __restrict__ Y,
                                                       float* __restrict__ out) {
  __shared__ unsigned short tile[64 * 260];
  int b = blockIdx.x >> 6;
  int lt = blockIdx.x & 63;
  int t = threadIdx.x;
  for (int i = t; i < 4096; i += 256) {
    int r = i >> 6;
    int c4 = (i & 63) << 2;
    ushort4 v = *(const ushort4*)&Y[((size_t)b * 4096 + lt * 64 + r) * 256 + c4];
    *(ushort4*)&tile[r * 260 + c4] = v;
  }
  __syncthreads();
  for (int i = t; i < 4096; i += 256) {
    int c = i >> 4;
    int l4 = (i & 15) << 2;
    float4 v;
    v.x = bf2f(tile[(l4 + 0) * 260 + c]);
    v.y = bf2f(tile[(l4 + 1) * 260 + c]);
    v.z = bf2f(tile[(l4 + 2) * 260 + c]);
    v.w = bf2f(tile[(l4 + 3) * 260 + c]);
    *(float4*)&out[((size_t)b * 256 + c) * 4096 + lt * 64 + l4] = v;
  }
}

extern "C" void kernel_launch(void* const* d_in, const int* in_sizes, int n_in,
                              void* d_out, int out_size, void* d_ws, size_t ws_size,
                              hipStream_t stream) {
  const float* x = (const float*)d_in[0];
  const float* w1 = (const float*)d_in[1];
  const float* b1 = (const float*)d_in[2];
  const float* bn1_g = (const float*)d_in[3];
  const float* bn1_b = (const float*)d_in[4];
  const float* w2 = (const float*)d_in[5];
  const float* b2 = (const float*)d_in[6];
  const float* bn2_g = (const float*)d_in[7];
  const float* bn2_b = (const float*)d_in[8];
  const float* cw1 = (const float*)d_in[9];
  const float* cb1 = (const float*)d_in[10];
  const float* gn1_g = (const float*)d_in[11];
  const float* gn1_b = (const float*)d_in[12];
  const float* gn2_g = (const float*)d_in[13];
  const float* gn2_b = (const float*)d_in[14];
  const float* cw2 = (const float*)d_in[15];
  const float* cb2 = (const float*)d_in[16];
  const float* gn3_g = (const float*)d_in[17];
  const float* gn3_b = (const float*)d_in[18];

  const size_t SZ = (size_t)16 * 256 * 4096;

  char* p = (char*)d_ws;
  unsigned short* Ybf = (unsigned short*)p;  p += SZ * 2;   // bf16 T state
  unsigned short* C1 = (unsigned short*)p;   p += SZ * 2;
  unsigned short* Fb = (unsigned short*)p;   p += SZ * 2;
  unsigned short* APK1 = (unsigned short*)p; p += (size_t)24 * 16 * 64 * 8 * 2;
  unsigned short* APK2 = (unsigned short*)p; p += (size_t)24 * 16 * 64 * 8 * 2;
  unsigned short* APKS = (unsigned short*)p; p += (size_t)6 * 16 * 64 * 8 * 2;
  float* TP1 = (float*)p;                    p += 768 * 4;
  float* TP2 = (float*)p;                    p += 768 * 4;
  float* STATS = (float*)p;                  p += 1024 * 4;
  float* P1 = (float*)p;                     p += (size_t)16 * 32 * 128 * 4;
  float* P2 = (float*)p;                     p += (size_t)16 * 32 * 128 * 4;
  float* P3 = (float*)p;                     p += (size_t)16 * 32 * 128 * 4;

  unsigned short* Qbf = (unsigned short*)d_out;   // stem conv2-out scratch (bf16 C-layout)
  unsigned short* Y1 = (unsigned short*)d_out;    // y1 bf16 (first 32 MB)
  unsigned short* YB = Y1 + SZ;                   // ybase bf16 (second 32 MB)

  // ---- weight packing ----
  pack_big<<<96, 256, 0, stream>>>(cw1, APK1, TP1);
  pack_big<<<96, 256, 0, stream>>>(cw2, APK2, TP2);
  pack_stem<<<24, 256, 0, stream>>>(w2, APKS);

  // ---- stem ----
  conv1_kernel<<<16384, 256, 0, stream>>>(x, w1, b1, C1);
  stats_bf16_kernel<<<64, 256, 0, stream>>>(C1, STATS, 4096, 16, 64 * 4096, 4096, 1.f / 65536.f);
  act_transpose64<<<1024, 256, 0, stream>>>(C1, STATS, bn1_g, bn1_b, Fb);
  gemm_T<6, 1, 64, 0, 0, 32, true, false, 2><<<1024, 256, 0, stream>>>(
      Fb, APKS, nullptr, nullptr, nullptr, nullptr, b2, 0.f, Qbf, nullptr);
  stats_bf16_kernel<<<256, 256, 0, stream>>>(Qbf, STATS, 4096, 16, 256 * 4096, 4096, 1.f / 65536.f);
  bn_tanh_T<<<512, 512, 0, stream>>>(Qbf, STATS, bn2_g, bn2_b, Ybf, P1);

  // ---- ODE: 8 steps (pred + 2 corr), bf16 T state in Ybf ----
  const float H = 0.125f;
  for (int i = 0; i < 8; i++) {
    float t = i * H;
    gemm_T<24, 3, 256, 1, 0, 32, true, true, 0><<<1024, 256, 0, stream>>>(
        Ybf, APK1, P1, gn1_g, gn1_b, TP1, cb1, t, C1, P2);
    gemm_T<24, 3, 256, 1, 1, 64, true, true, 0><<<1024, 256, 0, stream>>>(
        C1, APK2, P2, gn2_g, gn2_b, TP2, cb2, t, Fb, P3);
    combine_T<0><<<512, 512, 0, stream>>>(Fb, P3, gn3_g, gn3_b, Ybf, Y1, YB, P1);
    for (int c = 0; c < 2; c++) {
      gemm_T<24, 3, 256, 1, 0, 32, true, true, 0><<<1024, 256, 0, stream>>>(
          Y1, APK1, P1, gn1_g, gn1_b, TP1, cb1, t + H, C1, P2);
      gemm_T<24, 3, 256, 1, 1, 64, true, true, 0><<<1024, 256, 0, stream>>>(
          C1, APK2, P2, gn2_g, gn2_b, TP2, cb2, t + H, Fb, P3);
      if (c == 0)
        combine_T<1><<<512, 512, 0, stream>>>(Fb, P3, gn3_g, gn3_b, YB, Y1, nullptr, P1);
      else
        combine_T<2><<<512, 512, 0, stream>>>(Fb, P3, gn3_g, gn3_b, YB, Ybf, nullptr, P1);
    }
  }

  // ---- final: transpose bf16 T state -> d_out C layout fp32 ----
  transpose_final<<<1024, 256, 0, stream>>>(Ybf, (float*)d_out);
}

// Round 17
// 2169.007 us; speedup vs baseline: 1.1307x; 1.0450x over previous
//
#include <hip/hip_runtime.h>
#include <math.h>

#define L4 4096

typedef short bf16x8 __attribute__((ext_vector_type(8)));
typedef float f32x4 __attribute__((ext_vector_type(4)));

__device__ __forceinline__ unsigned short f2bf(float f) {
  unsigned u = __builtin_bit_cast(unsigned, f);
  return (unsigned short)((u + 0x7FFFu + ((u >> 16) & 1u)) >> 16);
}
__device__ __forceinline__ float bf2f(unsigned short h) {
  unsigned u = ((unsigned)h) << 16;
  return __builtin_bit_cast(float, u);
}
__device__ __forceinline__ unsigned pk2(float lo, float hi) {
  unsigned d;
  asm("v_cvt_pk_bf16_f32 %0, %1, %2" : "=v"(d) : "v"(lo), "v"(hi));
  return d;
}
__device__ __forceinline__ float fast_tanh(float x) {
  float e = __expf(2.f * x);
  return 1.f - 2.f * __builtin_amdgcn_rcpf(e + 1.f);
}

// ---------------- pack big conv weights: Apack[ks][frow][lane][8] + t-channel ----------------
__global__ __launch_bounds__(256) void pack_big(const float* __restrict__ cw,
                                                unsigned short* __restrict__ Apack,
                                                float* __restrict__ Tpack) {
  int gid = blockIdx.x * 256 + threadIdx.x;
  if (gid < 768) {
    int o = gid & 255, tap = gid >> 8;
    Tpack[tap * 256 + o] = cw[((size_t)o * 257) * 9 + 3 + tap];
  }
  if (gid >= 24 * 16 * 64) return;
  int ks = gid >> 10;
  int frow = (gid >> 6) & 15;
  int lane = gid & 63;
  int o = frow * 16 + (lane & 15);
  int tap = ks >> 3;
  int ib = ((ks & 7) << 5) + ((lane >> 4) << 3);
#pragma unroll
  for (int e = 0; e < 8; e++) {
    int i = ib + e;
    Apack[(size_t)gid * 8 + e] = f2bf(cw[((size_t)o * 257 + (i + 1)) * 9 + 3 + tap]);
  }
}

// ---------------- pack stem conv2 weights ----------------
__global__ __launch_bounds__(256) void pack_stem(const float* __restrict__ w2,
                                                 unsigned short* __restrict__ Apack) {
  int gid = blockIdx.x * 256 + threadIdx.x;
  if (gid >= 6 * 16 * 64) return;
  int ks = gid >> 10;
  int frow = (gid >> 6) & 15;
  int lane = gid & 63;
  int o = frow * 16 + (lane & 15);
  int tap = ks >> 1;
  int ib = ((ks & 1) << 5) + ((lane >> 4) << 3);
#pragma unroll
  for (int e = 0; e < 8; e++) {
    int i = ib + e;
    Apack[(size_t)gid * 8 + e] = f2bf(w2[((size_t)o * 64 + i) * 3 + tap]);
  }
}

// ---------------- stem conv1 ----------------
__global__ __launch_bounds__(256) void conv1_kernel(const float* __restrict__ x,
                                                    const float* __restrict__ w,
                                                    const float* __restrict__ bias,
                                                    unsigned short* __restrict__ out) {
  int idx = blockIdx.x * 256 + threadIdx.x;
  int l = idx & 4095;
  int c = (idx >> 12) & 63;
  int b = idx >> 18;
  const float* xb = x + (size_t)b * 4 * L4;
  const float* wc = w + c * 12;
  float acc = bias[c];
#pragma unroll
  for (int i = 0; i < 4; i++) {
    float x0 = (l > 0) ? xb[i * L4 + l - 1] : 0.f;
    float x1 = xb[i * L4 + l];
    float x2 = (l < 4095) ? xb[i * L4 + l + 1] : 0.f;
    acc += wc[i * 3] * x0 + wc[i * 3 + 1] * x1 + wc[i * 3 + 2] * x2;
  }
  out[idx] = f2bf(acc);
}

// ---------------- stats, bf16 input ----------------
__global__ __launch_bounds__(256) void stats_bf16_kernel(const unsigned short* __restrict__ in,
                                                         float* __restrict__ stats,
                                                         int unit_stride, int nrow,
                                                         int row_stride, int rowlen,
                                                         float inv_n) {
  int u = blockIdx.x;
  const unsigned short* base = in + (size_t)u * unit_stride;
  float s = 0.f, s2 = 0.f;
  for (int r = 0; r < nrow; r++) {
    const unsigned short* rowp = base + (size_t)r * row_stride;
    for (int j = threadIdx.x * 4; j < rowlen; j += 256 * 4) {
      ushort4 v = *(const ushort4*)(rowp + j);
      float va = bf2f(v.x), vb = bf2f(v.y), vc = bf2f(v.z), vd = bf2f(v.w);
      s += va + vb + vc + vd;
      s2 += va * va + vb * vb + vc * vc + vd * vd;
    }
  }
  __shared__ float sh[512];
  sh[threadIdx.x] = s;
  sh[256 + threadIdx.x] = s2;
  __syncthreads();
  for (int off = 128; off > 0; off >>= 1) {
    if (threadIdx.x < off) {
      sh[threadIdx.x] += sh[threadIdx.x + off];
      sh[256 + threadIdx.x] += sh[256 + threadIdx.x + off];
    }
    __syncthreads();
  }
  if (threadIdx.x == 0) {
    float m = sh[0] * inv_n;
    float var = sh[256] * inv_n - m * m;
    stats[u * 2] = m;
    stats[u * 2 + 1] = rsqrtf(var + 1e-5f);
  }
}

// ---------------- stem: BN1-affine + relu + bf16 + transpose to padded XT64 ----------------
__global__ __launch_bounds__(256) void act_transpose64(const unsigned short* __restrict__ inv,
                                                       const float* __restrict__ stats,
                                                       const float* __restrict__ gamma,
                                                       const float* __restrict__ beta,
                                                       unsigned short* __restrict__ Xt) {
  constexpr int C = 64;
  __shared__ unsigned short tile[64 * C];
  int bidx = blockIdx.x;
  int b = bidx >> 6;
  int lt = bidx & 63;
  int l0 = lt << 6;
  int t = threadIdx.x;
  int lanel = t & 63;
  int cq = t >> 6;
  for (int cp = 0; cp < C / 4; cp++) {
    int c = cp * 4 + cq;
    float m = stats[2 * c], rs = stats[2 * c + 1];
    float ga = gamma[c] * rs, be = beta[c] - m * ga;
    size_t gidx = ((size_t)b * C + c) * 4096 + l0 + lanel;
    float v = bf2f(inv[gidx]);
    float a = v * ga + be;
    float r = fmaxf(a, 0.f);
    int sw = (lanel & 15) << 2;
    tile[lanel * C + (c ^ sw)] = f2bf(r);
  }
  __syncthreads();
  constexpr int CH = C / 4;
  constexpr int RPP = 256 / CH;
  for (int p = 0; p < 64 / RPP; p++) {
    int r = p * RPP + t / CH;
    int ch = t % CH;
    int sw = (r & 15) << 2;
    ushort4 v = *(const ushort4*)&tile[r * C + ((ch * 4) ^ sw)];
    *(ushort4*)&Xt[((size_t)b * 4098 + 1 + l0 + r) * C + ch * 4] = v;
  }
  if (lt == 0) {
    if (t < C / 4) *(ushort4*)&Xt[((size_t)b * 4098 + 0) * C + t * 4] = make_ushort4(0, 0, 0, 0);
  } else if (lt == 63) {
    if (t < C / 4) *(ushort4*)&Xt[((size_t)b * 4098 + 4097) * C + t * 4] = make_ushort4(0, 0, 0, 0);
  }
}

// ---------------- fused MFMA conv-GEMM: 4 waves of 64o x 64l, coalesced LDS epilogue -----
// Tile 256o x 64l, 256 thr (4 waves). grid = 16b * 64 lt = 1024, 4 blocks/CU.
// OUT: 0 = T-layout bf16 + partials (LDS-staged coalesced store); 1 = fp32 C; 2 = bf16 C.
template <int NKS, int KLG, int CIN, int NORM, int ACT, int NCH, bool INBF, bool TCH, int OUT>
__global__ __launch_bounds__(256, 4) void gemm_T(const void* __restrict__ Bsrc,
                                                 const unsigned short* __restrict__ Apack,
                                                 const float* __restrict__ Pin,
                                                 const float* __restrict__ gng,
                                                 const float* __restrict__ gnb,
                                                 const float* __restrict__ Tpack,
                                                 const float* __restrict__ bias,
                                                 float tval,
                                                 void* __restrict__ outv,
                                                 float* __restrict__ Pout) {
  constexpr int CPR = CIN / 8;
  constexpr int CPRLG = (CIN == 256) ? 5 : 3;
  constexpr int ROWS = 66;
  constexpr int RPI = 256 >> CPRLG;
  constexpr int TOT = ROWS * CPR;
  constexpr int NIT = (TOT + 255) / 256;
  __shared__ unsigned short bsm[ROWS * CIN];   // B tile; reused as C tile in epilogue
  __shared__ float gsm[32][2];
  __shared__ float ebias[256];
  __shared__ float psh[32][2];

  int tid = threadIdx.x;
  int lane = tid & 63;
  int wv = tid >> 6;
  int b = blockIdx.x >> 6;
  int lt = blockIdx.x & 63;
  int l_base = lt << 6;
  int wo0 = wv << 6;
  int col = lane & 15;
  int grp = lane >> 4;

  // ---- phase 0: parallel GN-stat reduce (8-lane groups) + ebias precompute ----
  if (NORM) {
    int g = tid >> 3, j0 = tid & 7;
    const float* Pg = Pin + ((size_t)b * 32 + g) * 128;
    float s = 0.f, s2 = 0.f;
    for (int j = j0; j < NCH; j += 8) { s += Pg[j * 2]; s2 += Pg[j * 2 + 1]; }
#pragma unroll
    for (int off = 4; off; off >>= 1) { s += __shfl_down(s, off, 8); s2 += __shfl_down(s2, off, 8); }
    if (j0 == 0) {
      float m = s * (1.f / 32768.f);
      float var = s2 * (1.f / 32768.f) - m * m;
      gsm[g][0] = m;
      gsm[g][1] = rsqrtf(var + 1e-5f);
    }
  }
  {
    float e = bias[tid];
    if (TCH) e += tval * (Tpack[tid] + Tpack[256 + tid] + Tpack[512 + tid]);
    ebias[tid] = e;
  }
  if (OUT == 0 && tid < 32) { psh[tid][0] = 0.f; psh[tid][1] = 0.f; }
  __syncthreads();

  // ---- phase 1: stage B tile; linear LDS writes, source pre-swizzled ----
  {
    int pl = tid & (CPR - 1);
    int row0 = tid >> CPRLG;
    int gch = pl ^ (row0 & 7);
    float ga0 = 1.f, ga1 = 1.f, ga2 = 1.f, ga3 = 1.f, ga4 = 1.f, ga5 = 1.f, ga6 = 1.f, ga7 = 1.f;
    float be0 = 0.f, be1 = 0.f, be2 = 0.f, be3 = 0.f, be4 = 0.f, be5 = 0.f, be6 = 0.f, be7 = 0.f;
    if (NORM) {
      float m = gsm[gch][0], rs = gsm[gch][1];
      float4 g0 = *(const float4*)&gng[gch * 8];
      float4 g1 = *(const float4*)&gng[gch * 8 + 4];
      float4 b0 = *(const float4*)&gnb[gch * 8];
      float4 b1 = *(const float4*)&gnb[gch * 8 + 4];
      ga0 = g0.x * rs; ga1 = g0.y * rs; ga2 = g0.z * rs; ga3 = g0.w * rs;
      ga4 = g1.x * rs; ga5 = g1.y * rs; ga6 = g1.z * rs; ga7 = g1.w * rs;
      be0 = b0.x - m * ga0; be1 = b0.y - m * ga1; be2 = b0.z - m * ga2; be3 = b0.w - m * ga3;
      be4 = b1.x - m * ga4; be5 = b1.y - m * ga5; be6 = b1.z - m * ga6; be7 = b1.w - m * ga7;
    }
#define ACTF(a) ((ACT == 0) ? fmaxf((a), 0.f) : ((a) > 0.f ? (a) : __expf(a) - 1.f))
#pragma unroll
    for (int it = 0; it < NIT; it++) {
      int chunk = it * 256 + tid;
      if (chunk < TOT) {
        int row = row0 + it * RPI;
        uint4 w4;
        if (NORM) {
          int gl = l_base - 1 + row;
          if (gl >= 0 && gl < 4096) {
            size_t base = ((size_t)b * 4096 + gl) * CIN + gch * 8;
            float v0, v1, v2, v3, v4, v5, v6, v7;
            if (INBF) {
              uint4 raw = *(const uint4*)((const unsigned short*)Bsrc + base);
              v0 = bf2f((unsigned short)(raw.x & 0xFFFF)); v1 = bf2f((unsigned short)(raw.x >> 16));
              v2 = bf2f((unsigned short)(raw.y & 0xFFFF)); v3 = bf2f((unsigned short)(raw.y >> 16));
              v4 = bf2f((unsigned short)(raw.z & 0xFFFF)); v5 = bf2f((unsigned short)(raw.z >> 16));
              v6 = bf2f((unsigned short)(raw.w & 0xFFFF)); v7 = bf2f((unsigned short)(raw.w >> 16));
            } else {
              float4 r0 = *(const float4*)((const float*)Bsrc + base);
              float4 r1 = *(const float4*)((const float*)Bsrc + base + 4);
              v0 = r0.x; v1 = r0.y; v2 = r0.z; v3 = r0.w;
              v4 = r1.x; v5 = r1.y; v6 = r1.z; v7 = r1.w;
            }
            float r0 = ACTF(v0 * ga0 + be0), r1 = ACTF(v1 * ga1 + be1);
            float r2 = ACTF(v2 * ga2 + be2), r3 = ACTF(v3 * ga3 + be3);
            float r4 = ACTF(v4 * ga4 + be4), r5 = ACTF(v5 * ga5 + be5);
            float r6 = ACTF(v6 * ga6 + be6), r7 = ACTF(v7 * ga7 + be7);
            w4.x = pk2(r0, r1); w4.y = pk2(r2, r3);
            w4.z = pk2(r4, r5); w4.w = pk2(r6, r7);
          } else {
            w4 = make_uint4(0, 0, 0, 0);
          }
        } else {
          w4 = *(const uint4*)((const unsigned short*)Bsrc +
                               ((size_t)b * 4098 + l_base + row) * CIN + gch * 8);
        }
        *(uint4*)&bsm[(size_t)chunk * 8] = w4;
      }
    }
#undef ACTF
  }
  __syncthreads();

  // ---- phase 2: MFMA loop (4 B ds_reads feed 16 MFMAs per ks) ----
  const unsigned short* apk = Apack + (size_t)(wv * 4) * 512 + (size_t)lane * 8;

  f32x4 acc[4][4];
#pragma unroll
  for (int i = 0; i < 4; i++)
#pragma unroll
    for (int j = 0; j < 4; j++) acc[i][j] = (f32x4){0.f, 0.f, 0.f, 0.f};

  __builtin_amdgcn_s_setprio(1);
#pragma unroll
  for (int ks = 0; ks < NKS; ks++) {
    int tap = ks >> KLG;
    int cbase = (ks & ((1 << KLG) - 1)) << 2;
    int lr0 = col + tap;
    int cb = (cbase + grp) ^ (lr0 & 7);
    const unsigned short* bp = &bsm[((size_t)(lr0 << CPRLG) + cb) * 8];
    const unsigned short* ap = apk + (size_t)ks * 16 * 512;
    bf16x8 bfr[4], afr[4];
#pragma unroll
    for (int fc = 0; fc < 4; fc++) bfr[fc] = *(const bf16x8*)(bp + fc * 16 * CIN);
#pragma unroll
    for (int fo = 0; fo < 4; fo++) afr[fo] = *(const bf16x8*)(ap + fo * 512);
#pragma unroll
    for (int fo = 0; fo < 4; fo++)
#pragma unroll
      for (int fc = 0; fc < 4; fc++)
        acc[fo][fc] = __builtin_amdgcn_mfma_f32_16x16x32_bf16(afr[fo], bfr[fc], acc[fo][fc], 0, 0, 0);
  }
  __builtin_amdgcn_s_setprio(0);

  // ---- epilogue ----
  if (OUT == 0) __syncthreads();   // bsm free; reuse as C tile (64 rows x 512B, 16B-swizzled)

  float ps = 0.f, ps2 = 0.f;
#pragma unroll
  for (int fo = 0; fo < 4; fo++) {
    int o0 = wo0 + fo * 16 + grp * 4;
    float eb0 = ebias[o0], eb1 = ebias[o0 + 1], eb2 = ebias[o0 + 2], eb3 = ebias[o0 + 3];
    float w0c0 = 0.f, w0c1 = 0.f, w0c2 = 0.f, w0c3 = 0.f;
    float w2c0 = 0.f, w2c1 = 0.f, w2c2 = 0.f, w2c3 = 0.f;
    if (TCH && lt == 0) {
      w0c0 = tval * Tpack[o0]; w0c1 = tval * Tpack[o0 + 1];
      w0c2 = tval * Tpack[o0 + 2]; w0c3 = tval * Tpack[o0 + 3];
    }
    if (TCH && lt == 63) {
      w2c0 = tval * Tpack[512 + o0]; w2c1 = tval * Tpack[512 + o0 + 1];
      w2c2 = tval * Tpack[512 + o0 + 2]; w2c3 = tval * Tpack[512 + o0 + 3];
    }
#pragma unroll
    for (int fc = 0; fc < 4; fc++) {
      int lrow = fc * 16 + col;
      int l = l_base + lrow;
      float v0 = acc[fo][fc][0] + eb0;
      float v1 = acc[fo][fc][1] + eb1;
      float v2 = acc[fo][fc][2] + eb2;
      float v3 = acc[fo][fc][3] + eb3;
      if (TCH) {
        if (lt == 0 && l == 0) { v0 -= w0c0; v1 -= w0c1; v2 -= w0c2; v3 -= w0c3; }
        if (lt == 63 && l == 4095) { v0 -= w2c0; v1 -= w2c1; v2 -= w2c2; v3 -= w2c3; }
      }
      if (OUT == 0) {
        ps += v0 + v1 + v2 + v3;
        ps2 += v0 * v0 + v1 * v1 + v2 * v2 + v3 * v3;
        int ob = o0 * 2;                                   // byte offset within row
        int byte = lrow * 512 + ((ob & ~15) ^ ((lrow & 7) << 4)) + (ob & 15);
        *(uint2*)((char*)bsm + byte) = make_uint2(pk2(v0, v1), pk2(v2, v3));
      } else if (OUT == 1) {
        float* op = (float*)outv + ((size_t)b * 256 + o0) * 4096 + l;
        op[0] = v0; op[4096] = v1; op[8192] = v2; op[12288] = v3;
      } else {
        unsigned short* op = (unsigned short*)outv + ((size_t)b * 256 + o0) * 4096 + l;
        op[0] = f2bf(v0); op[4096] = f2bf(v1); op[8192] = f2bf(v2); op[12288] = f2bf(v3);
      }
    }
    if (OUT == 0) {
      float s = ps, s2 = ps2;
#pragma unroll
      for (int off = 8; off; off >>= 1) {
        s += __shfl_down(s, off, 16);
        s2 += __shfl_down(s2, off, 16);
      }
      if (col == 0) {
        int g = wv * 8 + fo * 2 + (grp >> 1);
        atomicAdd(&psh[g][0], s);
        atomicAdd(&psh[g][1], s2);
      }
      ps = 0.f; ps2 = 0.f;
    }
  }

  if (OUT == 0) {
    __syncthreads();
    // coalesced copy-out: 8 x uint4 per thread (2048 total = full 32KB tile);
    // 32 lanes cover 512B contiguous per row
#pragma unroll
    for (int it = 0; it < 8; it++) {
      int idx = it * 256 + tid;
      int r = idx >> 5;
      int c16 = idx & 31;
      int byte = r * 512 + ((c16 << 4) ^ ((r & 7) << 4));
      uint4 v = *(const uint4*)((const char*)bsm + byte);
      *(uint4*)((unsigned short*)outv + ((size_t)b * 4096 + l_base + r) * 256 + c16 * 8) = v;
    }
    if (tid < 32) {
      size_t pi = ((size_t)b * 32 + tid) * 128 + (size_t)lt * 2;
      Pout[pi] = psh[tid][0];
      Pout[pi + 1] = psh[tid][1];
    }
  }
}

// ---------------- stem: BN2-affine + fast-tanh (bf16 in), C->T transpose, y0 bf16 --------
__global__ __launch_bounds__(512) void bn_tanh_T(const unsigned short* __restrict__ Q,
                                                 const float* __restrict__ stats,
                                                 const float* __restrict__ gamma,
                                                 const float* __restrict__ beta,
                                                 unsigned short* __restrict__ Y,
                                                 float* __restrict__ P1) {
  int tid = threadIdx.x;
  int b = blockIdx.x >> 5;
  int seg = blockIdx.x & 31;
  int c = tid >> 1;
  float m = stats[2 * c], rs = stats[2 * c + 1];
  float ga = gamma[c] * rs, be = beta[c] - m * ga;
  __shared__ float psh[32][2];
  if (tid < 32) { psh[tid][0] = 0.f; psh[tid][1] = 0.f; }
  __syncthreads();
  float s = 0.f, s2 = 0.f;
  for (int it = 0; it < 16; it++) {
    int l4 = (tid & 1) + it * 2;
    int l0 = seg * 128 + l4 * 4;
    ushort4 v = *(const ushort4*)&Q[((size_t)b * 256 + c) * 4096 + l0];
    float r0 = fast_tanh(bf2f(v.x) * ga + be);
    float r1 = fast_tanh(bf2f(v.y) * ga + be);
    float r2 = fast_tanh(bf2f(v.z) * ga + be);
    float r3 = fast_tanh(bf2f(v.w) * ga + be);
    Y[((size_t)b * 4096 + l0 + 0) * 256 + c] = f2bf(r0);
    Y[((size_t)b * 4096 + l0 + 1) * 256 + c] = f2bf(r1);
    Y[((size_t)b * 4096 + l0 + 2) * 256 + c] = f2bf(r2);
    Y[((size_t)b * 4096 + l0 + 3) * 256 + c] = f2bf(r3);
    s += r0 + r1 + r2 + r3;
    s2 += r0 * r0 + r1 * r1 + r2 * r2 + r3 * r3;
  }
#pragma unroll
  for (int off = 8; off; off >>= 1) { s += __shfl_down(s, off, 16); s2 += __shfl_down(s2, off, 16); }
  if ((tid & 15) == 0) {
    int g = c >> 3;
    atomicAdd(&psh[g][0], s);
    atomicAdd(&psh[g][1], s2);
  }
  __syncthreads();
  if (tid < 32) {
    size_t pi = ((size_t)b * 32 + tid) * 128 + (size_t)seg * 2;
    P1[pi] = psh[tid][0];
    P1[pi + 1] = psh[tid][1];
  }
}

// ---------------- combine (T layout, bf16 state): GN3-affine(F) + Heun + P1 partials ----
template <int MODE>
__global__ __launch_bounds__(512) void combine_T(const unsigned short* __restrict__ F,
                                                 const float* __restrict__ P3,
                                                 const float* __restrict__ gng,
                                                 const float* __restrict__ gnb,
                                                 const unsigned short* __restrict__ Yin,
                                                 unsigned short* __restrict__ Out1,
                                                 unsigned short* __restrict__ OutB,
                                                 float* __restrict__ P1) {
  __shared__ float gsm[32][2];
  __shared__ float gabe[256][2];
  __shared__ float psh[32][2];
  int tid = threadIdx.x;
  int b = blockIdx.x >> 5;
  int seg = blockIdx.x & 31;
  {
    int g = tid >> 4, j0 = tid & 15;
    const float* Pg = P3 + ((size_t)b * 32 + g) * 128;
    float s = 0.f, s2 = 0.f;
    for (int j = j0; j < 64; j += 16) { s += Pg[j * 2]; s2 += Pg[j * 2 + 1]; }
#pragma unroll
    for (int off = 8; off; off >>= 1) { s += __shfl_down(s, off, 16); s2 += __shfl_down(s2, off, 16); }
    if (j0 == 0) {
      float m = s * (1.f / 32768.f);
      float var = s2 * (1.f / 32768.f) - m * m;
      gsm[g][0] = m;
      gsm[g][1] = rsqrtf(var + 1e-5f);
    }
  }
  __syncthreads();
  if (tid < 256) {
    float m = gsm[tid >> 3][0], rs = gsm[tid >> 3][1];
    float ga = gng[tid] * rs;
    gabe[tid][0] = ga;
    gabe[tid][1] = gnb[tid] - m * ga;
  }
  if (tid >= 256 && tid < 288) { psh[tid - 256][0] = 0.f; psh[tid - 256][1] = 0.f; }
  __syncthreads();

  size_t base4 = ((size_t)b * 4096 + seg * 128) * 64;
  int c0 = (tid << 2) & 255;
  int g = c0 >> 3;
  float ga0 = gabe[c0][0], be0 = gabe[c0][1];
  float ga1 = gabe[c0 + 1][0], be1 = gabe[c0 + 1][1];
  float ga2 = gabe[c0 + 2][0], be2 = gabe[c0 + 2][1];
  float ga3 = gabe[c0 + 3][0], be3 = gabe[c0 + 3][1];
  float s = 0.f, s2 = 0.f;
  for (int i = tid; i < 8192; i += 512) {
    size_t idx4 = base4 + i;
    ushort4 fv = ((const ushort4*)F)[idx4];
    ushort4 yv = ((const ushort4*)Yin)[idx4];
    float y0 = bf2f(yv.x), y1v = bf2f(yv.y), y2 = bf2f(yv.z), y3 = bf2f(yv.w);
    float f0 = bf2f(fv.x) * ga0 + be0;
    float f1 = bf2f(fv.y) * ga1 + be1;
    float f2 = bf2f(fv.z) * ga2 + be2;
    float f3 = bf2f(fv.w) * ga3 + be3;
    float yn0 = y0 + (MODE == 0 ? 0.125f : 0.0625f) * f0;
    float yn1 = y1v + (MODE == 0 ? 0.125f : 0.0625f) * f1;
    float yn2 = y2 + (MODE == 0 ? 0.125f : 0.0625f) * f2;
    float yn3 = y3 + (MODE == 0 ? 0.125f : 0.0625f) * f3;
    ((uint2*)Out1)[idx4] = make_uint2(pk2(yn0, yn1), pk2(yn2, yn3));
    if (MODE == 0) {
      float yb0 = y0 + 0.0625f * f0;
      float yb1 = y1v + 0.0625f * f1;
      float yb2 = y2 + 0.0625f * f2;
      float yb3 = y3 + 0.0625f * f3;
      ((uint2*)OutB)[idx4] = make_uint2(pk2(yb0, yb1), pk2(yb2, yb3));
    }
    s += yn0 + yn1 + yn2 + yn3;
    s2 += yn0 * yn0 + yn1 * yn1 + yn2 * yn2 + yn3 * yn3;
  }
  s += __shfl_xor(s, 1);
  s2 += __shfl_xor(s2, 1);
  if ((tid & 1) == 0) {
    atomicAdd(&psh[g][0], s);
    atomicAdd(&psh[g][1], s2);
  }
  __syncthreads();
  if (tid < 32) {
    size_t pi = ((size_t)b * 32 + tid) * 128 + (size_t)seg * 2;
    P1[pi] = psh[tid][0];
    P1[pi + 1] = psh[tid][1];
  }
}

// ---------------- final: T-layout bf16 -> C-layout fp32 (d_out) ----------------
__global__ __launch_bounds__(256) void transpose_final(const unsigned short* __restrict__ Y,
                                                       float* __restrict__ out) {
  __shared__ unsigned short tile[64 * 260];
  int b = blockIdx.x >> 6;
  int lt = blockIdx.x & 63;
  int t = threadIdx.x;
  for (int i = t; i < 4096; i += 256) {
    int r = i >> 6;
    int c4 = (i & 63) << 2;
    ushort4 v = *(const ushort4*)&Y[((size_t)b * 4096 + lt * 64 + r) * 256 + c4];
    *(ushort4*)&tile[r * 260 + c4] = v;
  }
  __syncthreads();
  for (int i = t; i < 4096; i += 256) {
    int c = i >> 4;
    int l4 = (i & 15) << 2;
    float4 v;
    v.x = bf2f(tile[(l4 + 0) * 260 + c]);
    v.y = bf2f(tile[(l4 + 1) * 260 + c]);
    v.z = bf2f(tile[(l4 + 2) * 260 + c]);
    v.w = bf2f(tile[(l4 + 3) * 260 + c]);
    *(float4*)&out[((size_t)b * 256 + c) * 4096 + lt * 64 + l4] = v;
  }
}

extern "C" void kernel_launch(void* const* d_in, const int* in_sizes, int n_in,
                              void* d_out, int out_size, void* d_ws, size_t ws_size,
                              hipStream_t stream) {
  const float* x = (const float*)d_in[0];
  const float* w1 = (const float*)d_in[1];
  const float* b1 = (const float*)d_in[2];
  const float* bn1_g = (const float*)d_in[3];
  const float* bn1_b = (const float*)d_in[4];
  const float* w2 = (const float*)d_in[5];
  const float* b2 = (const float*)d_in[6];
  const float* bn2_g = (const float*)d_in[7];
  const float* bn2_b = (const float*)d_in[8];
  const float* cw1 = (const float*)d_in[9];
  const float* cb1 = (const float*)d_in[10];
  const float* gn1_g = (const float*)d_in[11];
  const float* gn1_b = (const float*)d_in[12];
  const float* gn2_g = (const float*)d_in[13];
  const float* gn2_b = (const float*)d_in[14];
  const float* cw2 = (const float*)d_in[15];
  const float* cb2 = (const float*)d_in[16];
  const float* gn3_g = (const float*)d_in[17];
  const float* gn3_b = (const float*)d_in[18];

  const size_t SZ = (size_t)16 * 256 * 4096;

  char* p = (char*)d_ws;
  unsigned short* Ybf = (unsigned short*)p;  p += SZ * 2;   // bf16 T state
  unsigned short* C1 = (unsigned short*)p;   p += SZ * 2;
  unsigned short* Fb = (unsigned short*)p;   p += SZ * 2;
  unsigned short* APK1 = (unsigned short*)p; p += (size_t)24 * 16 * 64 * 8 * 2;
  unsigned short* APK2 = (unsigned short*)p; p += (size_t)24 * 16 * 64 * 8 * 2;
  unsigned short* APKS = (unsigned short*)p; p += (size_t)6 * 16 * 64 * 8 * 2;
  float* TP1 = (float*)p;                    p += 768 * 4;
  float* TP2 = (float*)p;                    p += 768 * 4;
  float* STATS = (float*)p;                  p += 1024 * 4;
  float* P1 = (float*)p;                     p += (size_t)16 * 32 * 128 * 4;
  float* P2 = (float*)p;                     p += (size_t)16 * 32 * 128 * 4;
  float* P3 = (float*)p;                     p += (size_t)16 * 32 * 128 * 4;

  unsigned short* Qbf = (unsigned short*)d_out;   // stem conv2-out scratch (bf16 C-layout)
  unsigned short* Y1 = (unsigned short*)d_out;    // y1 bf16 (first 32 MB)
  unsigned short* YB = Y1 + SZ;                   // ybase bf16 (second 32 MB)

  // ---- weight packing ----
  pack_big<<<96, 256, 0, stream>>>(cw1, APK1, TP1);
  pack_big<<<96, 256, 0, stream>>>(cw2, APK2, TP2);
  pack_stem<<<24, 256, 0, stream>>>(w2, APKS);

  // ---- stem ----
  conv1_kernel<<<16384, 256, 0, stream>>>(x, w1, b1, C1);
  stats_bf16_kernel<<<64, 256, 0, stream>>>(C1, STATS, 4096, 16, 64 * 4096, 4096, 1.f / 65536.f);
  act_transpose64<<<1024, 256, 0, stream>>>(C1, STATS, bn1_g, bn1_b, Fb);
  gemm_T<6, 1, 64, 0, 0, 32, true, false, 2><<<1024, 256, 0, stream>>>(
      Fb, APKS, nullptr, nullptr, nullptr, nullptr, b2, 0.f, Qbf, nullptr);
  stats_bf16_kernel<<<256, 256, 0, stream>>>(Qbf, STATS, 4096, 16, 256 * 4096, 4096, 1.f / 65536.f);
  bn_tanh_T<<<512, 512, 0, stream>>>(Qbf, STATS, bn2_g, bn2_b, Ybf, P1);

  // ---- ODE: 8 steps (pred + 2 corr), bf16 T state in Ybf ----
  const float H = 0.125f;
  for (int i = 0; i < 8; i++) {
    float t = i * H;
    gemm_T<24, 3, 256, 1, 0, 32, true, true, 0><<<1024, 256, 0, stream>>>(
        Ybf, APK1, P1, gn1_g, gn1_b, TP1, cb1, t, C1, P2);
    gemm_T<24, 3, 256, 1, 1, 64, true, true, 0><<<1024, 256, 0, stream>>>(
        C1, APK2, P2, gn2_g, gn2_b, TP2, cb2, t, Fb, P3);
    combine_T<0><<<512, 512, 0, stream>>>(Fb, P3, gn3_g, gn3_b, Ybf, Y1, YB, P1);
    for (int c = 0; c < 2; c++) {
      gemm_T<24, 3, 256, 1, 0, 32, true, true, 0><<<1024, 256, 0, stream>>>(
          Y1, APK1, P1, gn1_g, gn1_b, TP1, cb1, t + H, C1, P2);
      gemm_T<24, 3, 256, 1, 1, 64, true, true, 0><<<1024, 256, 0, stream>>>(
          C1, APK2, P2, gn2_g, gn2_b, TP2, cb2, t + H, Fb, P3);
      if (c == 0)
        combine_T<1><<<512, 512, 0, stream>>>(Fb, P3, gn3_g, gn3_b, YB, Y1, nullptr, P1);
      else
        combine_T<2><<<512, 512, 0, stream>>>(Fb, P3, gn3_g, gn3_b, YB, Ybf, nullptr, P1);
    }
  }

  // ---- final: transpose bf16 T state -> d_out C layout fp32 ----
  transpose_final<<<1024, 256, 0, stream>>>(Ybf, (float*)d_out);
}